// Round 2
// baseline (1447.963 us; speedup 1.0000x reference)
//
#include <hip/hip_runtime.h>

typedef __attribute__((ext_vector_type(8))) __bf16 bf16x8;
typedef __attribute__((ext_vector_type(4))) float floatx4;

__device__ __forceinline__ float bf2f(unsigned short u) {
    return __uint_as_float(((unsigned)u) << 16);
}
__device__ __forceinline__ unsigned short f2bf(float f) {
    unsigned u = __float_as_uint(f);
    unsigned r = u + 0x7FFFu + ((u >> 16) & 1u);
    return (unsigned short)(r >> 16);
}
// monotone float<->uint ordering for atomicMax on floats
__device__ __forceinline__ unsigned encf(float f) {
    unsigned u = __float_as_uint(f);
    return (u & 0x80000000u) ? ~u : (u | 0x80000000u);
}
__device__ __forceinline__ float decf(unsigned k) {
    unsigned u = (k & 0x80000000u) ? (k & 0x7FFFFFFFu) : ~k;
    return __uint_as_float(u);
}

// ---------------------------------------------------------------------------
// Dtype sniffing: if the float tensors are bf16, even-indexed ushorts of x are
// plausible bf16 values (N(0,1) -> exponent near 127). If they are fp32, the
// even-indexed ushorts are the LOW mantissa bits of fp32 (little-endian) ->
// near-uniform bits -> plausible exponent only ~25% of the time.
__global__ void detect_k(const unsigned short* __restrict__ xs, int* __restrict__ flag) {
    __shared__ int sred[256];
    int tid = threadIdx.x;
    int cnt = 0;
    for (int j = 0; j < 16; ++j) {
        unsigned short u = xs[(tid * 16 + j) * 2];
        int e = (u >> 7) & 0xFF;
        cnt += (e >= 96 && e <= 159) ? 1 : 0;
    }
    sred[tid] = cnt;
    __syncthreads();
    for (int s = 128; s > 0; s >>= 1) {
        if (tid < s) sred[tid] += sred[tid + s];
        __syncthreads();
    }
    if (tid == 0) *flag = (sred[0] > 2048) ? 1 : 0;  // 1 = bf16, 0 = fp32
}

// canonicalize a float tensor (bf16 or fp32 in memory) into bf16. cnt % 8 == 0.
__global__ void canon_k(const void* __restrict__ src, unsigned short* __restrict__ dst,
                        long long cnt, const int* __restrict__ flag) {
    long long idx = ((long long)blockIdx.x * 256 + threadIdx.x) * 8;
    if (idx >= cnt) return;
    if (*flag) {
        *(uint4*)&dst[idx] = *(const uint4*)((const unsigned short*)src + idx);
    } else {
        const float* sf = (const float*)src;
        unsigned short v[8];
        for (int j = 0; j < 8; ++j) v[j] = f2bf(sf[idx + j]);
        *(uint4*)&dst[idx] = *(const uint4*)v;
    }
}

// ---------------------------------------------------------------------------
// wsvec[r][k] = sum_h W_src[r][k][h]*att_src[r][h];  wdvec likewise.
__global__ void vec_kernel(const unsigned short* __restrict__ Ws,
                           const unsigned short* __restrict__ Wd,
                           const unsigned short* __restrict__ as_,
                           const unsigned short* __restrict__ ad_,
                           float* __restrict__ vecs) {
    int r = blockIdx.x;        // 0..1
    int k = threadIdx.x;       // 0..255
    float s = 0.f, t = 0.f;
    const unsigned short* wsrow = Ws + (size_t)r * 32768 + (size_t)k * 128;
    const unsigned short* wdrow = Wd + (size_t)r * 32768 + (size_t)k * 128;
    for (int h = 0; h < 128; ++h) {
        s += bf2f(wsrow[h]) * bf2f(as_[r * 128 + h]);
        t += bf2f(wdrow[h]) * bf2f(ad_[r * 128 + h]);
    }
    vecs[(r * 2 + 0) * 256 + k] = s;
    vecs[(r * 2 + 1) * 256 + k] = t;
}

// Bt[r][n][k] = W_src[r][k][n]  (bf16, transposed for k-contiguous MFMA frags)
__global__ void transpose_W(const unsigned short* __restrict__ W,
                            unsigned short* __restrict__ Bt) {
    int i = blockIdx.x * 256 + threadIdx.x;
    if (i >= 2 * 256 * 128) return;
    int r = i >> 15, rem = i & 32767;
    int k = rem >> 7, n = rem & 127;
    Bt[(size_t)r * 32768 + n * 256 + k] = W[i];
}

// ---------------------------------------------------------------------------
// per node: a_src0/a_dst0/a_src1/a_dst1 = dot(x[i], vecs[j]) — one wave/row
__global__ __launch_bounds__(256) void a_kernel(const unsigned short* __restrict__ x,
                                                const float* __restrict__ vecs,
                                                float* __restrict__ aout, int n) {
    __shared__ float sv[1024];
    int tid = threadIdx.x;
    for (int j = 0; j < 4; ++j) sv[j * 256 + tid] = vecs[j * 256 + tid];
    __syncthreads();
    int lane = tid & 63, wave = tid >> 6;
    int row = blockIdx.x * 4 + wave;
    if (row >= n) return;
    uint2 u = *(const uint2*)&x[(size_t)row * 256 + lane * 4];
    float xf[4];
    xf[0] = bf2f((unsigned short)(u.x & 0xFFFF));
    xf[1] = bf2f((unsigned short)(u.x >> 16));
    xf[2] = bf2f((unsigned short)(u.y & 0xFFFF));
    xf[3] = bf2f((unsigned short)(u.y >> 16));
    float s[4] = {0.f, 0.f, 0.f, 0.f};
    for (int j = 0; j < 4; ++j)
        for (int q = 0; q < 4; ++q)
            s[j] += xf[q] * sv[j * 256 + lane * 4 + q];
    for (int j = 0; j < 4; ++j)
        for (int off = 32; off > 0; off >>= 1)
            s[j] += __shfl_down(s[j], off);
    if (lane == 0)
        for (int j = 0; j < 4; ++j) aout[(size_t)j * n + row] = s[j];
}

// ---------------------------------------------------------------------------
// h[r] = x @ W_src[r]  (bf16 in, bf16 out).  Tile: 128 rows x 128 cols, BK=32.
__global__ __launch_bounds__(256) void gemm_h(const unsigned short* __restrict__ x,
                                              const unsigned short* __restrict__ Btg,
                                              unsigned short* __restrict__ hout, int n) {
    const int r = blockIdx.y;
    const unsigned short* bt = Btg + (size_t)r * 32768;
    unsigned short* h = hout + (size_t)r * n * 128;
    const int r0 = blockIdx.x * 128;
    __shared__ __align__(16) unsigned short As[128 * 40];
    __shared__ __align__(16) unsigned short Bs[128 * 40];
    int tid = threadIdx.x;
    int lane = tid & 63, wave = tid >> 6;

    floatx4 acc[2][8];
    for (int mt = 0; mt < 2; ++mt)
        for (int nt = 0; nt < 8; ++nt)
            acc[mt][nt] = (floatx4){0.f, 0.f, 0.f, 0.f};

    for (int k0 = 0; k0 < 256; k0 += 32) {
        for (int i = 0; i < 2; ++i) {
            int L = i * 256 + tid;
            int row = L >> 2, kc = (L & 3) * 8;
            uint4 va = make_uint4(0u, 0u, 0u, 0u);
            int gr = r0 + row;
            if (gr < n) va = *(const uint4*)&x[(size_t)gr * 256 + k0 + kc];
            *(uint4*)&As[row * 40 + kc] = va;
            uint4 vb = *(const uint4*)&bt[(size_t)row * 256 + k0 + kc];
            *(uint4*)&Bs[row * 40 + kc] = vb;
        }
        __syncthreads();
        int qk = (lane >> 4) * 8;
        int m16 = lane & 15;
        bf16x8 af[2], bfv[8];
        af[0] = *(const bf16x8*)&As[(wave * 32 + m16) * 40 + qk];
        af[1] = *(const bf16x8*)&As[(wave * 32 + 16 + m16) * 40 + qk];
        for (int nt = 0; nt < 8; ++nt)
            bfv[nt] = *(const bf16x8*)&Bs[(nt * 16 + m16) * 40 + qk];
        for (int mt = 0; mt < 2; ++mt)
            for (int nt = 0; nt < 8; ++nt)
                acc[mt][nt] = __builtin_amdgcn_mfma_f32_16x16x32_bf16(
                    af[mt], bfv[nt], acc[mt][nt], 0, 0, 0);
        __syncthreads();
    }
    // C/D layout: col = lane&15, row = (lane>>4)*4 + reg  (m89-verified)
    int col0 = lane & 15;
    for (int mt = 0; mt < 2; ++mt) {
        int baser = r0 + wave * 32 + mt * 16 + (lane >> 4) * 4;
        for (int nt = 0; nt < 8; ++nt)
            for (int i = 0; i < 4; ++i) {
                int gr = baser + i;
                if (gr < n) h[(size_t)gr * 128 + nt * 16 + col0] = f2bf(acc[mt][nt][i]);
            }
    }
}

// ---------------------------------------------------------------------------
// Pass A: e = leaky_relu(a_src[s]+a_dst[d]); store e; segment max via atomicMax
__global__ void edge_max(const int* __restrict__ ei, const float* __restrict__ as_,
                         const float* __restrict__ ad_, unsigned* __restrict__ menc,
                         float* __restrict__ ebuf, int E_, int n) {
    int t = blockIdx.x * 256 + threadIdx.x;
    int tot = E_ + n;
    if (t >= tot) return;
    int s, d;
    if (t < E_) { s = ei[t]; d = ei[E_ + t]; } else { s = t - E_; d = s; }
    float e = as_[s] + ad_[d];
    e = e > 0.f ? e : 0.2f * e;
    ebuf[t] = e;
    atomicMax(&menc[d], encf(e));
}

// Pass B: ex = exp(e - m[d]); denom via atomicAdd
__global__ void edge_exp(const int* __restrict__ ei, const unsigned* __restrict__ menc,
                         float* __restrict__ ebuf, float* __restrict__ dsum,
                         int E_, int n) {
    int t = blockIdx.x * 256 + threadIdx.x;
    int tot = E_ + n;
    if (t >= tot) return;
    int d = (t < E_) ? ei[E_ + t] : (t - E_);
    float ex = __expf(fminf(ebuf[t] - decf(menc[d]), 0.f));
    ebuf[t] = ex;
    unsafeAtomicAdd(&dsum[d], ex);
}

// Pass C: acc[d] += alpha * h[s]  — 128 threads per edge, 2 edges per block
__global__ __launch_bounds__(256) void scatter_k(const int* __restrict__ ei,
                                                 const float* __restrict__ ebuf,
                                                 const float* __restrict__ dsum,
                                                 const unsigned short* __restrict__ h,
                                                 float* __restrict__ acc,
                                                 int E_, int n) {
    int t = threadIdx.x;
    long long eidx = (long long)blockIdx.x * 2 + (t >> 7);
    int col = t & 127;
    long long tot = (long long)E_ + n;
    if (eidx >= tot) return;
    int s, d;
    if (eidx < E_) { s = ei[eidx]; d = ei[E_ + eidx]; }
    else           { s = (int)(eidx - E_); d = s; }
    float alpha = ebuf[eidx] / (dsum[d] + 1e-16f);
    float hv = bf2f(h[(size_t)s * 128 + col]);
    unsafeAtomicAdd(&acc[(size_t)d * 128 + col], alpha * hv);
}

// out = elu(acc + b0 + b1) -> bf16 or fp32 per flag
__global__ void finalize_k(const float* __restrict__ acc,
                           const unsigned short* __restrict__ bias,
                           void* __restrict__ out, long long total,
                           const int* __restrict__ flag) {
    long long i = (long long)blockIdx.x * 256 + threadIdx.x;
    if (i >= total) return;
    int col = (int)(i & 127);
    float v = acc[i] + bf2f(bias[col]) + bf2f(bias[128 + col]);
    v = v > 0.f ? v : (__expf(v) - 1.f);
    if (*flag) ((unsigned short*)out)[i] = f2bf(v);
    else       ((float*)out)[i] = v;
}

// ---------------------------------------------------------------------------
static inline char* carve(char*& p, size_t bytes) {
    char* r = p;
    p += (bytes + 255) & ~(size_t)255;
    return r;
}

extern "C" void kernel_launch(void* const* d_in, const int* in_sizes, int n_in,
                              void* d_out, int out_size, void* d_ws, size_t ws_size,
                              hipStream_t stream) {
    (void)n_in; (void)out_size; (void)ws_size;
    const void* x_raw  = d_in[0];
    const int*  ei0    = (const int*)d_in[1];
    const int*  ei1    = (const int*)d_in[2];
    const void* Ws_raw = d_in[3];
    const void* Wd_raw = d_in[4];
    const void* as_raw = d_in[5];
    const void* ad_raw = d_in[6];
    const void* b_raw  = d_in[7];

    const int n = in_sizes[0] / 256;   // 100000
    const int e = in_sizes[1] / 2;     // 1000000
    const int tot = e + n;

    // workspace carve-up
    char* p = (char*)d_ws;
    float*    acc   = (float*)carve(p, (size_t)n * 128 * 4);
    float*    dsum0 = (float*)carve(p, (size_t)4 * n * 4);   // dsum0,dsum1,menc0,menc1
    float*    dsum1 = dsum0 + n;
    unsigned* menc0 = (unsigned*)(dsum1 + n);
    unsigned* menc1 = menc0 + n;
    float*    avals = (float*)carve(p, (size_t)4 * n * 4);   // as0, ad0, as1, ad1
    float*    ex0   = (float*)carve(p, (size_t)tot * 4);
    float*    ex1   = (float*)carve(p, (size_t)tot * 4);
    float*    vecs  = (float*)carve(p, 1024 * 4);
    int*      flag  = (int*)carve(p, 256);
    unsigned short* xb   = (unsigned short*)carve(p, (size_t)n * 256 * 2);
    unsigned short* h0   = (unsigned short*)carve(p, (size_t)n * 128 * 2);
    unsigned short* h1   = (unsigned short*)carve(p, (size_t)n * 128 * 2);
    unsigned short* Wsb  = (unsigned short*)carve(p, 65536 * 2);
    unsigned short* Wdb  = (unsigned short*)carve(p, 65536 * 2);
    unsigned short* Bt   = (unsigned short*)carve(p, 65536 * 2);
    unsigned short* asb  = (unsigned short*)carve(p, 256 * 2);
    unsigned short* adb  = (unsigned short*)carve(p, 256 * 2);
    unsigned short* bsb  = (unsigned short*)carve(p, 256 * 2);

    hipMemsetAsync(acc, 0, (size_t)n * 128 * 4, stream);
    hipMemsetAsync(dsum0, 0, (size_t)4 * n * 4, stream);

    detect_k<<<1, 256, 0, stream>>>((const unsigned short*)x_raw, flag);

    long long cx = (long long)n * 256;
    canon_k<<<(int)((cx / 8 + 255) / 256), 256, 0, stream>>>(x_raw, xb, cx, flag);
    canon_k<<<32, 256, 0, stream>>>(Ws_raw, Wsb, 65536, flag);
    canon_k<<<32, 256, 0, stream>>>(Wd_raw, Wdb, 65536, flag);
    canon_k<<<1, 32, 0, stream>>>(as_raw, asb, 256, flag);
    canon_k<<<1, 32, 0, stream>>>(ad_raw, adb, 256, flag);
    canon_k<<<1, 32, 0, stream>>>(b_raw, bsb, 256, flag);

    vec_kernel<<<2, 256, 0, stream>>>(Wsb, Wdb, asb, adb, vecs);
    transpose_W<<<(2 * 256 * 128 + 255) / 256, 256, 0, stream>>>(Wsb, Bt);
    a_kernel<<<(n + 3) / 4, 256, 0, stream>>>(xb, vecs, avals, n);
    gemm_h<<<dim3((n + 127) / 128, 2), 256, 0, stream>>>(xb, Bt, h0, n);

    int gb = (tot + 255) / 256;
    edge_max<<<gb, 256, 0, stream>>>(ei0, avals, avals + n, menc0, ex0, e, n);
    edge_max<<<gb, 256, 0, stream>>>(ei1, avals + 2 * (size_t)n, avals + 3 * (size_t)n,
                                     menc1, ex1, e, n);
    edge_exp<<<gb, 256, 0, stream>>>(ei0, menc0, ex0, dsum0, e, n);
    edge_exp<<<gb, 256, 0, stream>>>(ei1, menc1, ex1, dsum1, e, n);

    int sb = (tot + 1) / 2;
    scatter_k<<<sb, 256, 0, stream>>>(ei0, ex0, dsum0, h0, acc, e, n);
    scatter_k<<<sb, 256, 0, stream>>>(ei1, ex1, dsum1, h1, acc, e, n);

    long long totout = (long long)n * 128;
    finalize_k<<<(int)((totout + 255) / 256), 256, 0, stream>>>(acc, bsb, d_out, totout, flag);
}

// Round 3
// 879.948 us; speedup vs baseline: 1.6455x; 1.6455x over previous
//
#include <hip/hip_runtime.h>

typedef __attribute__((ext_vector_type(8))) __bf16 bf16x8;
typedef __attribute__((ext_vector_type(4))) float floatx4;

__device__ __forceinline__ float bf2f(unsigned short u) {
    return __uint_as_float(((unsigned)u) << 16);
}
__device__ __forceinline__ unsigned short f2bf(float f) {
    unsigned u = __float_as_uint(f);
    unsigned r = u + 0x7FFFu + ((u >> 16) & 1u);
    return (unsigned short)(r >> 16);
}

// ---------------------------------------------------------------------------
// Dtype sniffing (see R1 notes): bf16 tensors -> even ushorts have sane
// exponents ~100% of the time; fp32 tensors -> ~25%.
__global__ void detect_k(const unsigned short* __restrict__ xs, int* __restrict__ flag) {
    __shared__ int sred[256];
    int tid = threadIdx.x;
    int cnt = 0;
    for (int j = 0; j < 16; ++j) {
        unsigned short u = xs[(tid * 16 + j) * 2];
        int e = (u >> 7) & 0xFF;
        cnt += (e >= 96 && e <= 159) ? 1 : 0;
    }
    sred[tid] = cnt;
    __syncthreads();
    for (int s = 128; s > 0; s >>= 1) {
        if (tid < s) sred[tid] += sred[tid + s];
        __syncthreads();
    }
    if (tid == 0) *flag = (sred[0] > 2048) ? 1 : 0;  // 1 = bf16, 0 = fp32
}

// canonicalize a float tensor (bf16 or fp32 in memory) into bf16. cnt % 8 == 0.
__global__ void canon_k(const void* __restrict__ src, unsigned short* __restrict__ dst,
                        long long cnt, const int* __restrict__ flag) {
    long long idx = ((long long)blockIdx.x * 256 + threadIdx.x) * 8;
    if (idx >= cnt) return;
    if (*flag) {
        *(uint4*)&dst[idx] = *(const uint4*)((const unsigned short*)src + idx);
    } else {
        const float* sf = (const float*)src;
        unsigned short v[8];
        for (int j = 0; j < 8; ++j) v[j] = f2bf(sf[idx + j]);
        *(uint4*)&dst[idx] = *(const uint4*)v;
    }
}

// ---------------------------------------------------------------------------
// wsvec[r][k] = sum_h W_src[r][k][h]*att_src[r][h];  wdvec likewise.
__global__ void vec_kernel(const unsigned short* __restrict__ Ws,
                           const unsigned short* __restrict__ Wd,
                           const unsigned short* __restrict__ as_,
                           const unsigned short* __restrict__ ad_,
                           float* __restrict__ vecs) {
    int r = blockIdx.x;        // 0..1
    int k = threadIdx.x;       // 0..255
    float s = 0.f, t = 0.f;
    const unsigned short* wsrow = Ws + (size_t)r * 32768 + (size_t)k * 128;
    const unsigned short* wdrow = Wd + (size_t)r * 32768 + (size_t)k * 128;
    for (int h = 0; h < 128; ++h) {
        s += bf2f(wsrow[h]) * bf2f(as_[r * 128 + h]);
        t += bf2f(wdrow[h]) * bf2f(ad_[r * 128 + h]);
    }
    vecs[(r * 2 + 0) * 256 + k] = s;
    vecs[(r * 2 + 1) * 256 + k] = t;
}

// Bt[r][n][k] = W_src[r][k][n]  (bf16, transposed for k-contiguous MFMA frags)
__global__ void transpose_W(const unsigned short* __restrict__ W,
                            unsigned short* __restrict__ Bt) {
    int i = blockIdx.x * 256 + threadIdx.x;
    if (i >= 2 * 256 * 128) return;
    int r = i >> 15, rem = i & 32767;
    int k = rem >> 7, n = rem & 127;
    Bt[(size_t)r * 32768 + n * 256 + k] = W[i];
}

// ---------------------------------------------------------------------------
// per node: a_src0/a_dst0/a_src1/a_dst1 = dot(x[i], vecs[j]) — one wave/row
__global__ __launch_bounds__(256) void a_kernel(const unsigned short* __restrict__ x,
                                                const float* __restrict__ vecs,
                                                float* __restrict__ aout, int n) {
    __shared__ float sv[1024];
    int tid = threadIdx.x;
    for (int j = 0; j < 4; ++j) sv[j * 256 + tid] = vecs[j * 256 + tid];
    __syncthreads();
    int lane = tid & 63, wave = tid >> 6;
    int row = blockIdx.x * 4 + wave;
    if (row >= n) return;
    uint2 u = *(const uint2*)&x[(size_t)row * 256 + lane * 4];
    float xf[4];
    xf[0] = bf2f((unsigned short)(u.x & 0xFFFF));
    xf[1] = bf2f((unsigned short)(u.x >> 16));
    xf[2] = bf2f((unsigned short)(u.y & 0xFFFF));
    xf[3] = bf2f((unsigned short)(u.y >> 16));
    float s[4] = {0.f, 0.f, 0.f, 0.f};
    for (int j = 0; j < 4; ++j)
        for (int q = 0; q < 4; ++q)
            s[j] += xf[q] * sv[j * 256 + lane * 4 + q];
    for (int j = 0; j < 4; ++j)
        for (int off = 32; off > 0; off >>= 1)
            s[j] += __shfl_down(s[j], off);
    if (lane == 0)
        for (int j = 0; j < 4; ++j) aout[(size_t)j * n + row] = s[j];
}

// ---------------------------------------------------------------------------
// h[r] = x @ W_src[r]  (bf16 in, bf16 out).  Tile: 128 rows x 128 cols, BK=32.
__global__ __launch_bounds__(256) void gemm_h(const unsigned short* __restrict__ x,
                                              const unsigned short* __restrict__ Btg,
                                              unsigned short* __restrict__ hout, int n) {
    const int r = blockIdx.y;
    const unsigned short* bt = Btg + (size_t)r * 32768;
    unsigned short* h = hout + (size_t)r * n * 128;
    const int r0 = blockIdx.x * 128;
    __shared__ __align__(16) unsigned short As[128 * 40];
    __shared__ __align__(16) unsigned short Bs[128 * 40];
    int tid = threadIdx.x;
    int lane = tid & 63, wave = tid >> 6;

    floatx4 acc[2][8];
    for (int mt = 0; mt < 2; ++mt)
        for (int nt = 0; nt < 8; ++nt)
            acc[mt][nt] = (floatx4){0.f, 0.f, 0.f, 0.f};

    for (int k0 = 0; k0 < 256; k0 += 32) {
        for (int i = 0; i < 2; ++i) {
            int L = i * 256 + tid;
            int row = L >> 2, kc = (L & 3) * 8;
            uint4 va = make_uint4(0u, 0u, 0u, 0u);
            int gr = r0 + row;
            if (gr < n) va = *(const uint4*)&x[(size_t)gr * 256 + k0 + kc];
            *(uint4*)&As[row * 40 + kc] = va;
            uint4 vb = *(const uint4*)&bt[(size_t)row * 256 + k0 + kc];
            *(uint4*)&Bs[row * 40 + kc] = vb;
        }
        __syncthreads();
        int qk = (lane >> 4) * 8;
        int m16 = lane & 15;
        bf16x8 af[2], bfv[8];
        af[0] = *(const bf16x8*)&As[(wave * 32 + m16) * 40 + qk];
        af[1] = *(const bf16x8*)&As[(wave * 32 + 16 + m16) * 40 + qk];
        for (int nt = 0; nt < 8; ++nt)
            bfv[nt] = *(const bf16x8*)&Bs[(nt * 16 + m16) * 40 + qk];
        for (int mt = 0; mt < 2; ++mt)
            for (int nt = 0; nt < 8; ++nt)
                acc[mt][nt] = __builtin_amdgcn_mfma_f32_16x16x32_bf16(
                    af[mt], bfv[nt], acc[mt][nt], 0, 0, 0);
        __syncthreads();
    }
    // C/D layout: col = lane&15, row = (lane>>4)*4 + reg  (m89-verified)
    int col0 = lane & 15;
    for (int mt = 0; mt < 2; ++mt) {
        int baser = r0 + wave * 32 + mt * 16 + (lane >> 4) * 4;
        for (int nt = 0; nt < 8; ++nt)
            for (int i = 0; i < 4; ++i) {
                int gr = baser + i;
                if (gr < n) h[(size_t)gr * 128 + nt * 16 + col0] = f2bf(acc[mt][nt][i]);
            }
    }
}

// ---------------------------------------------------------------------------
// CSR build: histogram of dst, chunked single-block scan, then scatter-fill.
__global__ void hist_k(const int* __restrict__ ei, int* __restrict__ cnt,
                       int E_, int n) {
    int t = blockIdx.x * 256 + threadIdx.x;
    if (t >= E_ + n) return;
    int d = (t < E_) ? ei[E_ + t] : (t - E_);
    atomicAdd(&cnt[d], 1);
}

__global__ __launch_bounds__(1024) void scan_k(const int* __restrict__ cnt0,
                                               int* __restrict__ off0,
                                               const int* __restrict__ cnt1,
                                               int* __restrict__ off1, int n) {
    const int* cnt = blockIdx.x ? cnt1 : cnt0;
    int* off = blockIdx.x ? off1 : off0;
    __shared__ int sums[1024];
    int t = threadIdx.x;
    int chunk = (n + 1023) >> 10;
    int lo = t * chunk, hi = min(lo + chunk, n);
    int s = 0;
    for (int i = lo; i < hi; ++i) s += cnt[i];
    sums[t] = s;
    __syncthreads();
    for (int o = 1; o < 1024; o <<= 1) {
        int v = (t >= o) ? sums[t - o] : 0;
        __syncthreads();
        sums[t] += v;
        __syncthreads();
    }
    int base = (t == 0) ? 0 : sums[t - 1];
    for (int i = lo; i < hi; ++i) { off[i] = base; base += cnt[i]; }
}

// fill: e = leaky_relu(a_src[s] + a_dst[d]); place (s, e) at off[d]++.
// After this kernel, off[d] == segment END of node d (off[d-1] == start).
__global__ void fill_k(const int* __restrict__ ei, const float* __restrict__ as_,
                       const float* __restrict__ ad_, int* __restrict__ off,
                       int* __restrict__ srcs, float* __restrict__ evals,
                       int E_, int n) {
    int t = blockIdx.x * 256 + threadIdx.x;
    if (t >= E_ + n) return;
    int s, d;
    if (t < E_) { s = ei[t]; d = ei[E_ + t]; } else { s = t - E_; d = s; }
    float e = as_[s] + ad_[d];
    e = e > 0.f ? e : 0.2f * e;
    int pos = atomicAdd(&off[d], 1);
    srcs[pos] = s;
    evals[pos] = e;
}

// ---------------------------------------------------------------------------
// One wave per dst node, both relations fused, bias+ELU+store fused.
__device__ __forceinline__ void rel_acc(int d, int lane,
                                        const int* __restrict__ off,
                                        const int* __restrict__ srcs,
                                        const float* __restrict__ evals,
                                        const unsigned short* __restrict__ h,
                                        float& o0, float& o1) {
    int s0 = d ? off[d - 1] : 0;
    int e0 = off[d];
    float m = -1e30f;
    for (int i = s0 + lane; i < e0; i += 64) m = fmaxf(m, evals[i]);
    for (int o = 1; o < 64; o <<= 1) m = fmaxf(m, __shfl_xor(m, o));
    float denom = 0.f, a0 = 0.f, a1 = 0.f;
    for (int i = s0; i < e0; ++i) {
        float w = __expf(evals[i] - m);
        denom += w;
        unsigned hv = *(const unsigned*)&h[(size_t)srcs[i] * 128 + lane * 2];
        a0 += w * bf2f((unsigned short)(hv & 0xFFFFu));
        a1 += w * bf2f((unsigned short)(hv >> 16));
    }
    float inv = 1.f / (denom + 1e-16f);
    o0 = a0 * inv;
    o1 = a1 * inv;
}

__global__ __launch_bounds__(256) void agg_k(
    const int* __restrict__ off0, const int* __restrict__ src0,
    const float* __restrict__ ev0, const int* __restrict__ off1,
    const int* __restrict__ src1, const float* __restrict__ ev1,
    const unsigned short* __restrict__ h0, const unsigned short* __restrict__ h1,
    const unsigned short* __restrict__ bias, void* __restrict__ out,
    int n, const int* __restrict__ flag) {
    int wave = threadIdx.x >> 6, lane = threadIdx.x & 63;
    int d = blockIdx.x * 4 + wave;
    if (d >= n) return;
    float p0, p1, q0, q1;
    rel_acc(d, lane, off0, src0, ev0, h0, p0, p1);
    rel_acc(d, lane, off1, src1, ev1, h1, q0, q1);
    int c0 = lane * 2, c1 = c0 + 1;
    float v0 = p0 + q0 + bf2f(bias[c0]) + bf2f(bias[128 + c0]);
    float v1 = p1 + q1 + bf2f(bias[c1]) + bf2f(bias[128 + c1]);
    v0 = v0 > 0.f ? v0 : (__expf(v0) - 1.f);
    v1 = v1 > 0.f ? v1 : (__expf(v1) - 1.f);
    if (*flag) {
        unsigned pk = ((unsigned)f2bf(v1) << 16) | (unsigned)f2bf(v0);
        ((unsigned*)out)[(size_t)d * 64 + lane] = pk;
    } else {
        ((float2*)out)[(size_t)d * 64 + lane] = make_float2(v0, v1);
    }
}

// ---------------------------------------------------------------------------
static inline char* carve(char*& p, size_t bytes) {
    char* r = p;
    p += (bytes + 255) & ~(size_t)255;
    return r;
}

extern "C" void kernel_launch(void* const* d_in, const int* in_sizes, int n_in,
                              void* d_out, int out_size, void* d_ws, size_t ws_size,
                              hipStream_t stream) {
    (void)n_in; (void)out_size; (void)ws_size;
    const void* x_raw  = d_in[0];
    const int*  ei0    = (const int*)d_in[1];
    const int*  ei1    = (const int*)d_in[2];
    const void* Ws_raw = d_in[3];
    const void* Wd_raw = d_in[4];
    const void* as_raw = d_in[5];
    const void* ad_raw = d_in[6];
    const void* b_raw  = d_in[7];

    const int n = in_sizes[0] / 256;   // 100000
    const int e = in_sizes[1] / 2;     // 1000000
    const int tot = e + n;

    // workspace carve-up
    char* p = (char*)d_ws;
    float* avals = (float*)carve(p, (size_t)4 * n * 4);   // as0, ad0, as1, ad1
    int*   cnt0  = (int*)carve(p, (size_t)2 * n * 4);     // cnt0 + cnt1 (one memset)
    int*   cnt1  = cnt0 + n;
    int*   off0  = (int*)carve(p, (size_t)n * 4);
    int*   off1  = (int*)carve(p, (size_t)n * 4);
    int*   src0  = (int*)carve(p, (size_t)tot * 4);
    int*   src1  = (int*)carve(p, (size_t)tot * 4);
    float* ev0   = (float*)carve(p, (size_t)tot * 4);
    float* ev1   = (float*)carve(p, (size_t)tot * 4);
    float* vecs  = (float*)carve(p, 1024 * 4);
    int*   flag  = (int*)carve(p, 256);
    unsigned short* xb  = (unsigned short*)carve(p, (size_t)n * 256 * 2);
    unsigned short* h0  = (unsigned short*)carve(p, (size_t)n * 128 * 2);
    unsigned short* h1  = (unsigned short*)carve(p, (size_t)n * 128 * 2);
    unsigned short* Wsb = (unsigned short*)carve(p, 65536 * 2);
    unsigned short* Wdb = (unsigned short*)carve(p, 65536 * 2);
    unsigned short* Bt  = (unsigned short*)carve(p, 65536 * 2);
    unsigned short* asb = (unsigned short*)carve(p, 256 * 2);
    unsigned short* adb = (unsigned short*)carve(p, 256 * 2);
    unsigned short* bsb = (unsigned short*)carve(p, 256 * 2);

    hipMemsetAsync(cnt0, 0, (size_t)2 * n * 4, stream);

    detect_k<<<1, 256, 0, stream>>>((const unsigned short*)x_raw, flag);

    long long cx = (long long)n * 256;
    canon_k<<<(int)((cx / 8 + 255) / 256), 256, 0, stream>>>(x_raw, xb, cx, flag);
    canon_k<<<32, 256, 0, stream>>>(Ws_raw, Wsb, 65536, flag);
    canon_k<<<32, 256, 0, stream>>>(Wd_raw, Wdb, 65536, flag);
    canon_k<<<1, 32, 0, stream>>>(as_raw, asb, 256, flag);
    canon_k<<<1, 32, 0, stream>>>(ad_raw, adb, 256, flag);
    canon_k<<<1, 32, 0, stream>>>(b_raw, bsb, 256, flag);

    int gb = (tot + 255) / 256;
    hist_k<<<gb, 256, 0, stream>>>(ei0, cnt0, e, n);
    hist_k<<<gb, 256, 0, stream>>>(ei1, cnt1, e, n);
    scan_k<<<2, 1024, 0, stream>>>(cnt0, off0, cnt1, off1, n);

    vec_kernel<<<2, 256, 0, stream>>>(Wsb, Wdb, asb, adb, vecs);
    transpose_W<<<(2 * 256 * 128 + 255) / 256, 256, 0, stream>>>(Wsb, Bt);
    a_kernel<<<(n + 3) / 4, 256, 0, stream>>>(xb, vecs, avals, n);
    gemm_h<<<dim3((n + 127) / 128, 2), 256, 0, stream>>>(xb, Bt, h0, n);

    fill_k<<<gb, 256, 0, stream>>>(ei0, avals, avals + n, off0, src0, ev0, e, n);
    fill_k<<<gb, 256, 0, stream>>>(ei1, avals + 2 * (size_t)n, avals + 3 * (size_t)n,
                                   off1, src1, ev1, e, n);

    agg_k<<<(n + 3) / 4, 256, 0, stream>>>(off0, src0, ev0, off1, src1, ev1,
                                           h0, h1, bsb, d_out, n, flag);
}

// Round 4
// 694.410 us; speedup vs baseline: 2.0852x; 1.2672x over previous
//
#include <hip/hip_runtime.h>

typedef __attribute__((ext_vector_type(8))) __bf16 bf16x8;
typedef __attribute__((ext_vector_type(4))) float floatx4;

__device__ __forceinline__ float bf2f(unsigned short u) {
    return __uint_as_float(((unsigned)u) << 16);
}
__device__ __forceinline__ unsigned short f2bf(float f) {
    unsigned u = __float_as_uint(f);
    unsigned r = u + 0x7FFFu + ((u >> 16) & 1u);
    return (unsigned short)(r >> 16);
}

// ---------------------------------------------------------------------------
// Dtype sniffing: bf16 tensors -> even ushorts have sane exponents ~100%;
// fp32 tensors (viewed as ushorts) -> ~25%.
__global__ void detect_k(const unsigned short* __restrict__ xs, int* __restrict__ flag) {
    __shared__ int sred[256];
    int tid = threadIdx.x;
    int cnt = 0;
    for (int j = 0; j < 16; ++j) {
        unsigned short u = xs[(tid * 16 + j) * 2];
        int e = (u >> 7) & 0xFF;
        cnt += (e >= 96 && e <= 159) ? 1 : 0;
    }
    sred[tid] = cnt;
    __syncthreads();
    for (int s = 128; s > 0; s >>= 1) {
        if (tid < s) sred[tid] += sred[tid + s];
        __syncthreads();
    }
    if (tid == 0) *flag = (sred[0] > 2048) ? 1 : 0;  // 1 = bf16, 0 = fp32
}

__device__ __forceinline__ void canon8(const void* src, unsigned short* dst,
                                       long long idx, int f) {
    if (f) {
        *(uint4*)&dst[idx] = *(const uint4*)((const unsigned short*)src + idx);
    } else {
        const float* sf = (const float*)src;
        unsigned short v[8];
        for (int j = 0; j < 8; ++j) v[j] = f2bf(sf[idx + j]);
        *(uint4*)&dst[idx] = *(const uint4*)v;
    }
}

// one launch canonicalizes Ws, Wd, att_src, att_dst, bias
__global__ void canon5_k(const void* Ws, const void* Wd, const void* as,
                         const void* ad, const void* b,
                         unsigned short* Wsb, unsigned short* Wdb,
                         unsigned short* asb, unsigned short* adb,
                         unsigned short* bsb, const int* __restrict__ flag) {
    int blk = blockIdx.x, tid = threadIdx.x;
    int f = *flag;
    if (blk < 64) {
        const void* src = blk < 32 ? Ws : Wd;
        unsigned short* dst = blk < 32 ? Wsb : Wdb;
        long long idx = ((long long)(blk & 31) * 256 + tid) * 8;
        canon8(src, dst, idx, f);
    } else {
        if (tid < 32)       canon8(as, asb, (long long)tid * 8, f);
        else if (tid < 64)  canon8(ad, adb, (long long)(tid - 32) * 8, f);
        else if (tid < 96)  canon8(b,  bsb, (long long)(tid - 64) * 8, f);
    }
}

// ---------------------------------------------------------------------------
// wsvec[r][k] = sum_h W_src[r][k][h]*att_src[r][h];  wdvec likewise.
__global__ void vec_kernel(const unsigned short* __restrict__ Ws,
                           const unsigned short* __restrict__ Wd,
                           const unsigned short* __restrict__ as_,
                           const unsigned short* __restrict__ ad_,
                           float* __restrict__ vecs) {
    int r = blockIdx.x;        // 0..1
    int k = threadIdx.x;       // 0..255
    float s = 0.f, t = 0.f;
    const unsigned short* wsrow = Ws + (size_t)r * 32768 + (size_t)k * 128;
    const unsigned short* wdrow = Wd + (size_t)r * 32768 + (size_t)k * 128;
    for (int h = 0; h < 128; ++h) {
        s += bf2f(wsrow[h]) * bf2f(as_[r * 128 + h]);
        t += bf2f(wdrow[h]) * bf2f(ad_[r * 128 + h]);
    }
    vecs[(r * 2 + 0) * 256 + k] = s;
    vecs[(r * 2 + 1) * 256 + k] = t;
}

// Bt[r][n][k] = W_src[r][k][n]  (bf16, transposed for k-contiguous MFMA frags)
__global__ void transpose_W(const unsigned short* __restrict__ W,
                            unsigned short* __restrict__ Bt) {
    int i = blockIdx.x * 256 + threadIdx.x;
    if (i >= 2 * 256 * 128) return;
    int r = i >> 15, rem = i & 32767;
    int k = rem >> 7, n = rem & 127;
    Bt[(size_t)r * 32768 + n * 256 + k] = W[i];
}

// ---------------------------------------------------------------------------
// Fused: canonicalize x into xb AND compute the 4 per-node attention scalars.
// One wave per row; lane covers 4 elements.
__global__ __launch_bounds__(256) void a_canon_k(const void* __restrict__ xraw,
                                                 unsigned short* __restrict__ xb,
                                                 const float* __restrict__ vecs,
                                                 float* __restrict__ aout, int n,
                                                 const int* __restrict__ flag) {
    __shared__ float sv[1024];
    int tid = threadIdx.x;
    for (int j = 0; j < 4; ++j) sv[j * 256 + tid] = vecs[j * 256 + tid];
    __syncthreads();
    int lane = tid & 63, wave = tid >> 6;
    int row = blockIdx.x * 4 + wave;
    if (row >= n) return;
    float xf[4];
    if (*flag) {
        uint2 u = *(const uint2*)((const unsigned short*)xraw + (size_t)row * 256 + lane * 4);
        xf[0] = bf2f((unsigned short)(u.x & 0xFFFF));
        xf[1] = bf2f((unsigned short)(u.x >> 16));
        xf[2] = bf2f((unsigned short)(u.y & 0xFFFF));
        xf[3] = bf2f((unsigned short)(u.y >> 16));
        *(uint2*)&xb[(size_t)row * 256 + lane * 4] = u;
    } else {
        float4 f = *(const float4*)((const float*)xraw + (size_t)row * 256 + lane * 4);
        xf[0] = f.x; xf[1] = f.y; xf[2] = f.z; xf[3] = f.w;
        unsigned short v[4] = {f2bf(f.x), f2bf(f.y), f2bf(f.z), f2bf(f.w)};
        *(uint2*)&xb[(size_t)row * 256 + lane * 4] = *(const uint2*)v;
    }
    float s[4] = {0.f, 0.f, 0.f, 0.f};
    for (int j = 0; j < 4; ++j)
        for (int q = 0; q < 4; ++q)
            s[j] += xf[q] * sv[j * 256 + lane * 4 + q];
    for (int j = 0; j < 4; ++j)
        for (int off = 32; off > 0; off >>= 1)
            s[j] += __shfl_down(s[j], off);
    if (lane == 0)
        for (int j = 0; j < 4; ++j) aout[(size_t)j * n + row] = s[j];
}

// ---------------------------------------------------------------------------
// h[r] = x @ W_src[r]  (bf16 in, bf16 out).  Tile: 128 rows x 128 cols, BK=32.
__global__ __launch_bounds__(256) void gemm_h(const unsigned short* __restrict__ x,
                                              const unsigned short* __restrict__ Btg,
                                              unsigned short* __restrict__ hout, int n) {
    const int r = blockIdx.y;
    const unsigned short* bt = Btg + (size_t)r * 32768;
    unsigned short* h = hout + (size_t)r * n * 128;
    const int r0 = blockIdx.x * 128;
    __shared__ __align__(16) unsigned short As[128 * 40];
    __shared__ __align__(16) unsigned short Bs[128 * 40];
    int tid = threadIdx.x;
    int lane = tid & 63, wave = tid >> 6;

    floatx4 acc[2][8];
    for (int mt = 0; mt < 2; ++mt)
        for (int nt = 0; nt < 8; ++nt)
            acc[mt][nt] = (floatx4){0.f, 0.f, 0.f, 0.f};

    for (int k0 = 0; k0 < 256; k0 += 32) {
        for (int i = 0; i < 2; ++i) {
            int L = i * 256 + tid;
            int row = L >> 2, kc = (L & 3) * 8;
            uint4 va = make_uint4(0u, 0u, 0u, 0u);
            int gr = r0 + row;
            if (gr < n) va = *(const uint4*)&x[(size_t)gr * 256 + k0 + kc];
            *(uint4*)&As[row * 40 + kc] = va;
            uint4 vb = *(const uint4*)&bt[(size_t)row * 256 + k0 + kc];
            *(uint4*)&Bs[row * 40 + kc] = vb;
        }
        __syncthreads();
        int qk = (lane >> 4) * 8;
        int m16 = lane & 15;
        bf16x8 af[2], bfv[8];
        af[0] = *(const bf16x8*)&As[(wave * 32 + m16) * 40 + qk];
        af[1] = *(const bf16x8*)&As[(wave * 32 + 16 + m16) * 40 + qk];
        for (int nt = 0; nt < 8; ++nt)
            bfv[nt] = *(const bf16x8*)&Bs[(nt * 16 + m16) * 40 + qk];
        for (int mt = 0; mt < 2; ++mt)
            for (int nt = 0; nt < 8; ++nt)
                acc[mt][nt] = __builtin_amdgcn_mfma_f32_16x16x32_bf16(
                    af[mt], bfv[nt], acc[mt][nt], 0, 0, 0);
        __syncthreads();
    }
    int col0 = lane & 15;
    for (int mt = 0; mt < 2; ++mt) {
        int baser = r0 + wave * 32 + mt * 16 + (lane >> 4) * 4;
        for (int nt = 0; nt < 8; ++nt)
            for (int i = 0; i < 4; ++i) {
                int gr = baser + i;
                if (gr < n) h[(size_t)gr * 128 + nt * 16 + col0] = f2bf(acc[mt][nt][i]);
            }
    }
}

// ---------------------------------------------------------------------------
// CSR build: histogram (both relations in one launch), scan, scatter-fill.
__global__ void hist2_k(const int* __restrict__ ei0, const int* __restrict__ ei1,
                        int* __restrict__ cnt0, int* __restrict__ cnt1,
                        int E_, int n) {
    int rel = blockIdx.y;
    const int* ei = rel ? ei1 : ei0;
    int* cnt = rel ? cnt1 : cnt0;
    int t = blockIdx.x * 256 + threadIdx.x;
    if (t >= E_ + n) return;
    int d = (t < E_) ? ei[E_ + t] : (t - E_);
    atomicAdd(&cnt[d], 1);
}

__global__ __launch_bounds__(1024) void scan_k(const int* __restrict__ cnt0,
                                               int* __restrict__ off0,
                                               const int* __restrict__ cnt1,
                                               int* __restrict__ off1, int n) {
    const int* cnt = blockIdx.x ? cnt1 : cnt0;
    int* off = blockIdx.x ? off1 : off0;
    __shared__ int sums[1024];
    int t = threadIdx.x;
    int chunk = (n + 1023) >> 10;
    int lo = t * chunk, hi = min(lo + chunk, n);
    int s = 0;
    for (int i = lo; i < hi; ++i) s += cnt[i];
    sums[t] = s;
    __syncthreads();
    for (int o = 1; o < 1024; o <<= 1) {
        int v = (t >= o) ? sums[t - o] : 0;
        __syncthreads();
        sums[t] += v;
        __syncthreads();
    }
    int base = (t == 0) ? 0 : sums[t - 1];
    for (int i = lo; i < hi; ++i) { off[i] = base; base += cnt[i]; }
}

// fill: e = leaky_relu(a_src[s]+a_dst[d]); pack (src,e) into 8B at off[d]++.
// After this kernel, off[d] == segment END of node d (off[d-1] == start).
__global__ void fill2_k(const int* __restrict__ ei0, const int* __restrict__ ei1,
                        const float* __restrict__ avals,
                        int* __restrict__ off0, int* __restrict__ off1,
                        unsigned long long* __restrict__ pair0,
                        unsigned long long* __restrict__ pair1,
                        int E_, int n) {
    int rel = blockIdx.y;
    const int* ei = rel ? ei1 : ei0;
    const float* as_ = avals + (rel ? 2 * (size_t)n : 0);
    const float* ad_ = avals + (rel ? 3 * (size_t)n : (size_t)n);
    int* off = rel ? off1 : off0;
    unsigned long long* pair = rel ? pair1 : pair0;
    int t = blockIdx.x * 256 + threadIdx.x;
    if (t >= E_ + n) return;
    int s, d;
    if (t < E_) { s = ei[t]; d = ei[E_ + t]; } else { s = t - E_; d = s; }
    float e = as_[s] + ad_[d];
    e = e > 0.f ? e : 0.2f * e;
    int pos = atomicAdd(&off[d], 1);
    pair[pos] = ((unsigned long long)__float_as_uint(e) << 32) | (unsigned)s;
}

// ---------------------------------------------------------------------------
// One wave per dst node; 4 groups x 16 lanes process 4 edges concurrently.
// Lane (g*16+l) loads h[src][l*8 .. l*8+8) — 16B per lane, 256B per row.
__device__ __forceinline__ void rel_acc4(int d, int g, int l, int lane,
                                         const int* __restrict__ off,
                                         const unsigned long long* __restrict__ pair,
                                         const unsigned short* __restrict__ h,
                                         float* __restrict__ o /*[8]*/) {
    int s0 = d ? off[d - 1] : 0;
    int e0 = off[d];
    float m = -1e30f;
    for (int i = s0 + lane; i < e0; i += 64)
        m = fmaxf(m, __uint_as_float((unsigned)(pair[i] >> 32)));
    for (int o_ = 1; o_ < 64; o_ <<= 1) m = fmaxf(m, __shfl_xor(m, o_));
    float denom = 0.f;
    float a[8] = {0.f, 0.f, 0.f, 0.f, 0.f, 0.f, 0.f, 0.f};
    for (int base = s0; base < e0; base += 4) {
        int i = base + g;
        if (i < e0) {
            unsigned long long pe = pair[i];
            int s = (int)(unsigned)pe;
            float ev = __uint_as_float((unsigned)(pe >> 32));
            float w = __expf(ev - m);
            denom += w;
            uint4 hv = *(const uint4*)&h[(size_t)s * 128 + l * 8];
            a[0] += w * bf2f((unsigned short)(hv.x & 0xFFFFu));
            a[1] += w * bf2f((unsigned short)(hv.x >> 16));
            a[2] += w * bf2f((unsigned short)(hv.y & 0xFFFFu));
            a[3] += w * bf2f((unsigned short)(hv.y >> 16));
            a[4] += w * bf2f((unsigned short)(hv.z & 0xFFFFu));
            a[5] += w * bf2f((unsigned short)(hv.z >> 16));
            a[6] += w * bf2f((unsigned short)(hv.w & 0xFFFFu));
            a[7] += w * bf2f((unsigned short)(hv.w >> 16));
        }
    }
    for (int j = 0; j < 8; ++j) {
        a[j] += __shfl_xor(a[j], 16);
        a[j] += __shfl_xor(a[j], 32);
    }
    denom += __shfl_xor(denom, 16);
    denom += __shfl_xor(denom, 32);
    float inv = 1.f / (denom + 1e-16f);
    for (int j = 0; j < 8; ++j) o[j] = a[j] * inv;
}

__global__ __launch_bounds__(256) void agg_k(
    const int* __restrict__ off0, const unsigned long long* __restrict__ pair0,
    const int* __restrict__ off1, const unsigned long long* __restrict__ pair1,
    const unsigned short* __restrict__ h0, const unsigned short* __restrict__ h1,
    const unsigned short* __restrict__ bias, void* __restrict__ out,
    int n, const int* __restrict__ flag) {
    int wave = threadIdx.x >> 6, lane = threadIdx.x & 63;
    int g = lane >> 4, l = lane & 15;
    int d = blockIdx.x * 4 + wave;
    if (d >= n) return;
    float p[8], q[8];
    rel_acc4(d, g, l, lane, off0, pair0, h0, p);
    rel_acc4(d, g, l, lane, off1, pair1, h1, q);
    // bias rows (bf16, contiguous 16B per lane's 8 cols)
    uint4 b0 = *(const uint4*)&bias[l * 8];
    uint4 b1 = *(const uint4*)&bias[128 + l * 8];
    const unsigned* b0u = (const unsigned*)&b0;
    const unsigned* b1u = (const unsigned*)&b1;
    float v[8];
    for (int j = 0; j < 8; ++j) {
        unsigned w0 = b0u[j >> 1], w1 = b1u[j >> 1];
        float bb = bf2f((unsigned short)((j & 1) ? (w0 >> 16) : (w0 & 0xFFFFu)))
                 + bf2f((unsigned short)((j & 1) ? (w1 >> 16) : (w1 & 0xFFFFu)));
        float t = p[j] + q[j] + bb;
        v[j] = t > 0.f ? t : (__expf(t) - 1.f);
    }
    if (g == 0) {
        if (*flag) {
            unsigned pk[4];
            for (int j = 0; j < 4; ++j)
                pk[j] = ((unsigned)f2bf(v[2 * j + 1]) << 16) | (unsigned)f2bf(v[2 * j]);
            ((uint4*)out)[(size_t)d * 16 + l] = *(const uint4*)pk;
        } else {
            float4 f0 = make_float4(v[0], v[1], v[2], v[3]);
            float4 f1 = make_float4(v[4], v[5], v[6], v[7]);
            ((float4*)out)[(size_t)d * 32 + l * 2] = f0;
            ((float4*)out)[(size_t)d * 32 + l * 2 + 1] = f1;
        }
    }
}

// ---------------------------------------------------------------------------
static inline char* carve(char*& p, size_t bytes) {
    char* r = p;
    p += (bytes + 255) & ~(size_t)255;
    return r;
}

extern "C" void kernel_launch(void* const* d_in, const int* in_sizes, int n_in,
                              void* d_out, int out_size, void* d_ws, size_t ws_size,
                              hipStream_t stream) {
    (void)n_in; (void)out_size; (void)ws_size;
    const void* x_raw  = d_in[0];
    const int*  ei0    = (const int*)d_in[1];
    const int*  ei1    = (const int*)d_in[2];
    const void* Ws_raw = d_in[3];
    const void* Wd_raw = d_in[4];
    const void* as_raw = d_in[5];
    const void* ad_raw = d_in[6];
    const void* b_raw  = d_in[7];

    const int n = in_sizes[0] / 256;   // 100000
    const int e = in_sizes[1] / 2;     // 1000000
    const int tot = e + n;

    // workspace carve-up
    char* p = (char*)d_ws;
    float* avals = (float*)carve(p, (size_t)4 * n * 4);   // as0, ad0, as1, ad1
    int*   cnt0  = (int*)carve(p, (size_t)2 * n * 4);     // cnt0 + cnt1 (one memset)
    int*   cnt1  = cnt0 + n;
    int*   off0  = (int*)carve(p, (size_t)n * 4);
    int*   off1  = (int*)carve(p, (size_t)n * 4);
    unsigned long long* pair0 = (unsigned long long*)carve(p, (size_t)tot * 8);
    unsigned long long* pair1 = (unsigned long long*)carve(p, (size_t)tot * 8);
    float* vecs  = (float*)carve(p, 1024 * 4);
    int*   flag  = (int*)carve(p, 256);
    unsigned short* xb  = (unsigned short*)carve(p, (size_t)n * 256 * 2);
    unsigned short* h0  = (unsigned short*)carve(p, (size_t)2 * n * 128 * 2); // h0+h1 contiguous
    unsigned short* h1  = h0 + (size_t)n * 128;
    unsigned short* Wsb = (unsigned short*)carve(p, 65536 * 2);
    unsigned short* Wdb = (unsigned short*)carve(p, 65536 * 2);
    unsigned short* Bt  = (unsigned short*)carve(p, 65536 * 2);
    unsigned short* asb = (unsigned short*)carve(p, 256 * 2);
    unsigned short* adb = (unsigned short*)carve(p, 256 * 2);
    unsigned short* bsb = (unsigned short*)carve(p, 256 * 2);

    hipMemsetAsync(cnt0, 0, (size_t)2 * n * 4, stream);

    detect_k<<<1, 256, 0, stream>>>((const unsigned short*)x_raw, flag);
    canon5_k<<<65, 256, 0, stream>>>(Ws_raw, Wd_raw, as_raw, ad_raw, b_raw,
                                     Wsb, Wdb, asb, adb, bsb, flag);
    vec_kernel<<<2, 256, 0, stream>>>(Wsb, Wdb, asb, adb, vecs);
    transpose_W<<<(2 * 256 * 128 + 255) / 256, 256, 0, stream>>>(Wsb, Bt);

    int gb = (tot + 255) / 256;
    hist2_k<<<dim3(gb, 2), 256, 0, stream>>>(ei0, ei1, cnt0, cnt1, e, n);
    scan_k<<<2, 1024, 0, stream>>>(cnt0, off0, cnt1, off1, n);

    a_canon_k<<<(n + 3) / 4, 256, 0, stream>>>(x_raw, xb, vecs, avals, n, flag);
    gemm_h<<<dim3((n + 127) / 128, 2), 256, 0, stream>>>(xb, Bt, h0, n);

    fill2_k<<<dim3(gb, 2), 256, 0, stream>>>(ei0, ei1, avals, off0, off1,
                                             pair0, pair1, e, n);

    agg_k<<<(n + 3) / 4, 256, 0, stream>>>(off0, pair0, off1, pair1,
                                           h0, h1, bsb, d_out, n, flag);
}

// Round 5
// 541.486 us; speedup vs baseline: 2.6741x; 1.2824x over previous
//
#include <hip/hip_runtime.h>

typedef __attribute__((ext_vector_type(8))) __bf16 bf16x8;
typedef __attribute__((ext_vector_type(4))) float floatx4;

__device__ __forceinline__ float bf2f(unsigned short u) {
    return __uint_as_float(((unsigned)u) << 16);
}
__device__ __forceinline__ unsigned short f2bf(float f) {
    unsigned u = __float_as_uint(f);
    unsigned r = u + 0x7FFFu + ((u >> 16) & 1u);
    return (unsigned short)(r >> 16);
}

// ---------------------------------------------------------------------------
// Dtype sniffing: bf16 tensors -> even ushorts have sane exponents ~100%;
// fp32 tensors (viewed as ushorts) -> ~25%.
__global__ void detect_k(const unsigned short* __restrict__ xs, int* __restrict__ flag) {
    __shared__ int sred[256];
    int tid = threadIdx.x;
    int cnt = 0;
    for (int j = 0; j < 16; ++j) {
        unsigned short u = xs[(tid * 16 + j) * 2];
        int e = (u >> 7) & 0xFF;
        cnt += (e >= 96 && e <= 159) ? 1 : 0;
    }
    sred[tid] = cnt;
    __syncthreads();
    for (int s = 128; s > 0; s >>= 1) {
        if (tid < s) sred[tid] += sred[tid + s];
        __syncthreads();
    }
    if (tid == 0) *flag = (sred[0] > 2048) ? 1 : 0;  // 1 = bf16, 0 = fp32
}

__device__ __forceinline__ void canon8(const void* src, unsigned short* dst,
                                       long long idx, int f) {
    if (f) {
        *(uint4*)&dst[idx] = *(const uint4*)((const unsigned short*)src + idx);
    } else {
        const float* sf = (const float*)src;
        unsigned short v[8];
        for (int j = 0; j < 8; ++j) v[j] = f2bf(sf[idx + j]);
        *(uint4*)&dst[idx] = *(const uint4*)v;
    }
}

// one launch canonicalizes Ws, Wd, att_src, att_dst, bias
__global__ void canon5_k(const void* Ws, const void* Wd, const void* as,
                         const void* ad, const void* b,
                         unsigned short* Wsb, unsigned short* Wdb,
                         unsigned short* asb, unsigned short* adb,
                         unsigned short* bsb, const int* __restrict__ flag) {
    int blk = blockIdx.x, tid = threadIdx.x;
    int f = *flag;
    if (blk < 64) {
        const void* src = blk < 32 ? Ws : Wd;
        unsigned short* dst = blk < 32 ? Wsb : Wdb;
        long long idx = ((long long)(blk & 31) * 256 + tid) * 8;
        canon8(src, dst, idx, f);
    } else {
        if (tid < 32)       canon8(as, asb, (long long)tid * 8, f);
        else if (tid < 64)  canon8(ad, adb, (long long)(tid - 32) * 8, f);
        else if (tid < 96)  canon8(b,  bsb, (long long)(tid - 64) * 8, f);
    }
}

// ---------------------------------------------------------------------------
// wsvec[r][k] = sum_h W_src[r][k][h]*att_src[r][h];  wdvec likewise.
__global__ void vec_kernel(const unsigned short* __restrict__ Ws,
                           const unsigned short* __restrict__ Wd,
                           const unsigned short* __restrict__ as_,
                           const unsigned short* __restrict__ ad_,
                           float* __restrict__ vecs) {
    int r = blockIdx.x;        // 0..1
    int k = threadIdx.x;       // 0..255
    float s = 0.f, t = 0.f;
    const unsigned short* wsrow = Ws + (size_t)r * 32768 + (size_t)k * 128;
    const unsigned short* wdrow = Wd + (size_t)r * 32768 + (size_t)k * 128;
    for (int h = 0; h < 128; ++h) {
        s += bf2f(wsrow[h]) * bf2f(as_[r * 128 + h]);
        t += bf2f(wdrow[h]) * bf2f(ad_[r * 128 + h]);
    }
    vecs[(r * 2 + 0) * 256 + k] = s;
    vecs[(r * 2 + 1) * 256 + k] = t;
}

// Bt[r][n][k] = W_src[r][k][n]  (bf16, transposed for k-contiguous MFMA frags)
__global__ void transpose_W(const unsigned short* __restrict__ W,
                            unsigned short* __restrict__ Bt) {
    int i = blockIdx.x * 256 + threadIdx.x;
    if (i >= 2 * 256 * 128) return;
    int r = i >> 15, rem = i & 32767;
    int k = rem >> 7, n = rem & 127;
    Bt[(size_t)r * 32768 + n * 256 + k] = W[i];
}

// ---------------------------------------------------------------------------
// Fused: canonicalize x into xb AND compute the 4 per-node attention scalars.
__global__ __launch_bounds__(256) void a_canon_k(const void* __restrict__ xraw,
                                                 unsigned short* __restrict__ xb,
                                                 const float* __restrict__ vecs,
                                                 float* __restrict__ aout, int n,
                                                 const int* __restrict__ flag) {
    __shared__ float sv[1024];
    int tid = threadIdx.x;
    for (int j = 0; j < 4; ++j) sv[j * 256 + tid] = vecs[j * 256 + tid];
    __syncthreads();
    int lane = tid & 63, wave = tid >> 6;
    int row = blockIdx.x * 4 + wave;
    if (row >= n) return;
    float xf[4];
    if (*flag) {
        uint2 u = *(const uint2*)((const unsigned short*)xraw + (size_t)row * 256 + lane * 4);
        xf[0] = bf2f((unsigned short)(u.x & 0xFFFF));
        xf[1] = bf2f((unsigned short)(u.x >> 16));
        xf[2] = bf2f((unsigned short)(u.y & 0xFFFF));
        xf[3] = bf2f((unsigned short)(u.y >> 16));
        *(uint2*)&xb[(size_t)row * 256 + lane * 4] = u;
    } else {
        float4 f = *(const float4*)((const float*)xraw + (size_t)row * 256 + lane * 4);
        xf[0] = f.x; xf[1] = f.y; xf[2] = f.z; xf[3] = f.w;
        unsigned short v[4] = {f2bf(f.x), f2bf(f.y), f2bf(f.z), f2bf(f.w)};
        *(uint2*)&xb[(size_t)row * 256 + lane * 4] = *(const uint2*)v;
    }
    float s[4] = {0.f, 0.f, 0.f, 0.f};
    for (int j = 0; j < 4; ++j)
        for (int q = 0; q < 4; ++q)
            s[j] += xf[q] * sv[j * 256 + lane * 4 + q];
    for (int j = 0; j < 4; ++j)
        for (int off = 32; off > 0; off >>= 1)
            s[j] += __shfl_down(s[j], off);
    if (lane == 0)
        for (int j = 0; j < 4; ++j) aout[(size_t)j * n + row] = s[j];
}

// ---------------------------------------------------------------------------
// h[r] = x @ W_src[r]  (bf16 in, bf16 out).  Tile: 128 rows x 128 cols, BK=32.
__global__ __launch_bounds__(256) void gemm_h(const unsigned short* __restrict__ x,
                                              const unsigned short* __restrict__ Btg,
                                              unsigned short* __restrict__ hout, int n) {
    const int r = blockIdx.y;
    const unsigned short* bt = Btg + (size_t)r * 32768;
    unsigned short* h = hout + (size_t)r * n * 128;
    const int r0 = blockIdx.x * 128;
    __shared__ __align__(16) unsigned short As[128 * 40];
    __shared__ __align__(16) unsigned short Bs[128 * 40];
    int tid = threadIdx.x;
    int lane = tid & 63, wave = tid >> 6;

    floatx4 acc[2][8];
    for (int mt = 0; mt < 2; ++mt)
        for (int nt = 0; nt < 8; ++nt)
            acc[mt][nt] = (floatx4){0.f, 0.f, 0.f, 0.f};

    for (int k0 = 0; k0 < 256; k0 += 32) {
        for (int i = 0; i < 2; ++i) {
            int L = i * 256 + tid;
            int row = L >> 2, kc = (L & 3) * 8;
            uint4 va = make_uint4(0u, 0u, 0u, 0u);
            int gr = r0 + row;
            if (gr < n) va = *(const uint4*)&x[(size_t)gr * 256 + k0 + kc];
            *(uint4*)&As[row * 40 + kc] = va;
            uint4 vb = *(const uint4*)&bt[(size_t)row * 256 + k0 + kc];
            *(uint4*)&Bs[row * 40 + kc] = vb;
        }
        __syncthreads();
        int qk = (lane >> 4) * 8;
        int m16 = lane & 15;
        bf16x8 af[2], bfv[8];
        af[0] = *(const bf16x8*)&As[(wave * 32 + m16) * 40 + qk];
        af[1] = *(const bf16x8*)&As[(wave * 32 + 16 + m16) * 40 + qk];
        for (int nt = 0; nt < 8; ++nt)
            bfv[nt] = *(const bf16x8*)&Bs[(nt * 16 + m16) * 40 + qk];
        for (int mt = 0; mt < 2; ++mt)
            for (int nt = 0; nt < 8; ++nt)
                acc[mt][nt] = __builtin_amdgcn_mfma_f32_16x16x32_bf16(
                    af[mt], bfv[nt], acc[mt][nt], 0, 0, 0);
        __syncthreads();
    }
    int col0 = lane & 15;
    for (int mt = 0; mt < 2; ++mt) {
        int baser = r0 + wave * 32 + mt * 16 + (lane >> 4) * 4;
        for (int nt = 0; nt < 8; ++nt)
            for (int i = 0; i < 4; ++i) {
                int gr = baser + i;
                if (gr < n) h[(size_t)gr * 128 + nt * 16 + col0] = f2bf(acc[mt][nt][i]);
            }
    }
}

// ---------------------------------------------------------------------------
// CSR build: histogram (both relations in one launch), 3-phase scan, fill.
__global__ void hist2_k(const int* __restrict__ ei0, const int* __restrict__ ei1,
                        int* __restrict__ cnt0, int* __restrict__ cnt1,
                        int E_, int n) {
    int rel = blockIdx.y;
    const int* ei = rel ? ei1 : ei0;
    int* cnt = rel ? cnt1 : cnt0;
    int t = blockIdx.x * 256 + threadIdx.x;
    if (t >= E_ + n) return;
    int d = (t < E_) ? ei[E_ + t] : (t - E_);
    atomicAdd(&cnt[d], 1);
}

// phase 1: per-block (256-elem tile) reduction -> partial[rel][b]
__global__ __launch_bounds__(256) void scan_red_k(const int* __restrict__ cnt0,
                                                  const int* __restrict__ cnt1,
                                                  int* __restrict__ part, // [2][nb]
                                                  int n, int nb) {
    __shared__ int s[256];
    int rel = blockIdx.y;
    const int* cnt = rel ? cnt1 : cnt0;
    int i = blockIdx.x * 256 + threadIdx.x;
    s[threadIdx.x] = (i < n) ? cnt[i] : 0;
    __syncthreads();
    for (int o = 128; o > 0; o >>= 1) {
        if (threadIdx.x < o) s[threadIdx.x] += s[threadIdx.x + o];
        __syncthreads();
    }
    if (threadIdx.x == 0) part[rel * nb + blockIdx.x] = s[0];
}

// phase 2: one block, exclusive-scan the partials per relation (nb <= 1024)
__global__ __launch_bounds__(1024) void scan_mid_k(int* __restrict__ part, int nb) {
    __shared__ int s[1024];
    int rel = blockIdx.x;
    int t = threadIdx.x;
    s[t] = (t < nb) ? part[rel * nb + t] : 0;
    __syncthreads();
    for (int o = 1; o < 1024; o <<= 1) {
        int v = (t >= o) ? s[t - o] : 0;
        __syncthreads();
        s[t] += v;
        __syncthreads();
    }
    if (t < nb) part[rel * nb + t] = (t == 0) ? 0 : s[t - 1];
}

// phase 3: block-local inclusive scan + base -> exclusive off[i]
__global__ __launch_bounds__(256) void scan_off_k(const int* __restrict__ cnt0,
                                                  const int* __restrict__ cnt1,
                                                  const int* __restrict__ part,
                                                  int* __restrict__ off0,
                                                  int* __restrict__ off1,
                                                  int n, int nb) {
    __shared__ int s[256];
    int rel = blockIdx.y;
    const int* cnt = rel ? cnt1 : cnt0;
    int* off = rel ? off1 : off0;
    int i = blockIdx.x * 256 + threadIdx.x;
    int t = threadIdx.x;
    int v = (i < n) ? cnt[i] : 0;
    s[t] = v;
    __syncthreads();
    for (int o = 1; o < 256; o <<= 1) {
        int u = (t >= o) ? s[t - o] : 0;
        __syncthreads();
        s[t] += u;
        __syncthreads();
    }
    if (i < n) off[i] = part[rel * nb + blockIdx.x] + s[t] - v;
}

// fill: e = leaky_relu(a_src[s]+a_dst[d]); pack (src,e) into 8B at off[d]++.
// After this kernel, off[d] == segment END of node d (off[d-1] == start).
__global__ void fill2_k(const int* __restrict__ ei0, const int* __restrict__ ei1,
                        const float* __restrict__ avals,
                        int* __restrict__ off0, int* __restrict__ off1,
                        unsigned long long* __restrict__ pair0,
                        unsigned long long* __restrict__ pair1,
                        int E_, int n) {
    int rel = blockIdx.y;
    const int* ei = rel ? ei1 : ei0;
    const float* as_ = avals + (rel ? 2 * (size_t)n : 0);
    const float* ad_ = avals + (rel ? 3 * (size_t)n : (size_t)n);
    int* off = rel ? off1 : off0;
    unsigned long long* pair = rel ? pair1 : pair0;
    int t = blockIdx.x * 256 + threadIdx.x;
    if (t >= E_ + n) return;
    int s, d;
    if (t < E_) { s = ei[t]; d = ei[E_ + t]; } else { s = t - E_; d = s; }
    float e = as_[s] + ad_[d];
    e = e > 0.f ? e : 0.2f * e;
    int pos = atomicAdd(&off[d], 1);
    pair[pos] = ((unsigned long long)__float_as_uint(e) << 32) | (unsigned)s;
}

// ---------------------------------------------------------------------------
// One wave per dst node; 4 groups x 16 lanes process 4 edges concurrently.
__device__ __forceinline__ void rel_acc4(int d, int g, int l, int lane,
                                         const int* __restrict__ off,
                                         const unsigned long long* __restrict__ pair,
                                         const unsigned short* __restrict__ h,
                                         float* __restrict__ o /*[8]*/) {
    int s0 = d ? off[d - 1] : 0;
    int e0 = off[d];
    float m = -1e30f;
    for (int i = s0 + lane; i < e0; i += 64)
        m = fmaxf(m, __uint_as_float((unsigned)(pair[i] >> 32)));
    for (int o_ = 1; o_ < 64; o_ <<= 1) m = fmaxf(m, __shfl_xor(m, o_));
    float denom = 0.f;
    float a[8] = {0.f, 0.f, 0.f, 0.f, 0.f, 0.f, 0.f, 0.f};
    for (int base = s0; base < e0; base += 4) {
        int i = base + g;
        if (i < e0) {
            unsigned long long pe = pair[i];
            int s = (int)(unsigned)pe;
            float ev = __uint_as_float((unsigned)(pe >> 32));
            float w = __expf(ev - m);
            denom += w;
            uint4 hv = *(const uint4*)&h[(size_t)s * 128 + l * 8];
            a[0] += w * bf2f((unsigned short)(hv.x & 0xFFFFu));
            a[1] += w * bf2f((unsigned short)(hv.x >> 16));
            a[2] += w * bf2f((unsigned short)(hv.y & 0xFFFFu));
            a[3] += w * bf2f((unsigned short)(hv.y >> 16));
            a[4] += w * bf2f((unsigned short)(hv.z & 0xFFFFu));
            a[5] += w * bf2f((unsigned short)(hv.z >> 16));
            a[6] += w * bf2f((unsigned short)(hv.w & 0xFFFFu));
            a[7] += w * bf2f((unsigned short)(hv.w >> 16));
        }
    }
    for (int j = 0; j < 8; ++j) {
        a[j] += __shfl_xor(a[j], 16);
        a[j] += __shfl_xor(a[j], 32);
    }
    denom += __shfl_xor(denom, 16);
    denom += __shfl_xor(denom, 32);
    float inv = 1.f / (denom + 1e-16f);
    for (int j = 0; j < 8; ++j) o[j] = a[j] * inv;
}

__global__ __launch_bounds__(256) void agg_k(
    const int* __restrict__ off0, const unsigned long long* __restrict__ pair0,
    const int* __restrict__ off1, const unsigned long long* __restrict__ pair1,
    const unsigned short* __restrict__ h0, const unsigned short* __restrict__ h1,
    const unsigned short* __restrict__ bias, void* __restrict__ out,
    int n, const int* __restrict__ flag) {
    int wave = threadIdx.x >> 6, lane = threadIdx.x & 63;
    int g = lane >> 4, l = lane & 15;
    int d = blockIdx.x * 4 + wave;
    if (d >= n) return;
    float p[8], q[8];
    rel_acc4(d, g, l, lane, off0, pair0, h0, p);
    rel_acc4(d, g, l, lane, off1, pair1, h1, q);
    uint4 b0 = *(const uint4*)&bias[l * 8];
    uint4 b1 = *(const uint4*)&bias[128 + l * 8];
    const unsigned* b0u = (const unsigned*)&b0;
    const unsigned* b1u = (const unsigned*)&b1;
    float v[8];
    for (int j = 0; j < 8; ++j) {
        unsigned w0 = b0u[j >> 1], w1 = b1u[j >> 1];
        float bb = bf2f((unsigned short)((j & 1) ? (w0 >> 16) : (w0 & 0xFFFFu)))
                 + bf2f((unsigned short)((j & 1) ? (w1 >> 16) : (w1 & 0xFFFFu)));
        float t = p[j] + q[j] + bb;
        v[j] = t > 0.f ? t : (__expf(t) - 1.f);
    }
    if (g == 0) {
        if (*flag) {
            unsigned pk[4];
            for (int j = 0; j < 4; ++j)
                pk[j] = ((unsigned)f2bf(v[2 * j + 1]) << 16) | (unsigned)f2bf(v[2 * j]);
            ((uint4*)out)[(size_t)d * 16 + l] = *(const uint4*)pk;
        } else {
            float4 f0 = make_float4(v[0], v[1], v[2], v[3]);
            float4 f1 = make_float4(v[4], v[5], v[6], v[7]);
            ((float4*)out)[(size_t)d * 32 + l * 2] = f0;
            ((float4*)out)[(size_t)d * 32 + l * 2 + 1] = f1;
        }
    }
}

// ---------------------------------------------------------------------------
static inline char* carve(char*& p, size_t bytes) {
    char* r = p;
    p += (bytes + 255) & ~(size_t)255;
    return r;
}

extern "C" void kernel_launch(void* const* d_in, const int* in_sizes, int n_in,
                              void* d_out, int out_size, void* d_ws, size_t ws_size,
                              hipStream_t stream) {
    (void)n_in; (void)out_size; (void)ws_size;
    const void* x_raw  = d_in[0];
    const int*  ei0    = (const int*)d_in[1];
    const int*  ei1    = (const int*)d_in[2];
    const void* Ws_raw = d_in[3];
    const void* Wd_raw = d_in[4];
    const void* as_raw = d_in[5];
    const void* ad_raw = d_in[6];
    const void* b_raw  = d_in[7];

    const int n = in_sizes[0] / 256;   // 100000
    const int e = in_sizes[1] / 2;     // 1000000
    const int tot = e + n;
    const int nb = (n + 255) / 256;    // scan blocks per relation (<=1024)

    // workspace carve-up
    char* p = (char*)d_ws;
    float* avals = (float*)carve(p, (size_t)4 * n * 4);   // as0, ad0, as1, ad1
    int*   cnt0  = (int*)carve(p, (size_t)2 * n * 4);     // cnt0 + cnt1 (one memset)
    int*   cnt1  = cnt0 + n;
    int*   off0  = (int*)carve(p, (size_t)n * 4);
    int*   off1  = (int*)carve(p, (size_t)n * 4);
    int*   part  = (int*)carve(p, (size_t)2 * nb * 4);
    unsigned long long* pair0 = (unsigned long long*)carve(p, (size_t)tot * 8);
    unsigned long long* pair1 = (unsigned long long*)carve(p, (size_t)tot * 8);
    float* vecs  = (float*)carve(p, 1024 * 4);
    int*   flag  = (int*)carve(p, 256);
    unsigned short* xb  = (unsigned short*)carve(p, (size_t)n * 256 * 2);
    unsigned short* h0  = (unsigned short*)carve(p, (size_t)2 * n * 128 * 2);
    unsigned short* h1  = h0 + (size_t)n * 128;
    unsigned short* Wsb = (unsigned short*)carve(p, 65536 * 2);
    unsigned short* Wdb = (unsigned short*)carve(p, 65536 * 2);
    unsigned short* Bt  = (unsigned short*)carve(p, 65536 * 2);
    unsigned short* asb = (unsigned short*)carve(p, 256 * 2);
    unsigned short* adb = (unsigned short*)carve(p, 256 * 2);
    unsigned short* bsb = (unsigned short*)carve(p, 256 * 2);

    hipMemsetAsync(cnt0, 0, (size_t)2 * n * 4, stream);

    detect_k<<<1, 256, 0, stream>>>((const unsigned short*)x_raw, flag);
    canon5_k<<<65, 256, 0, stream>>>(Ws_raw, Wd_raw, as_raw, ad_raw, b_raw,
                                     Wsb, Wdb, asb, adb, bsb, flag);
    vec_kernel<<<2, 256, 0, stream>>>(Wsb, Wdb, asb, adb, vecs);
    transpose_W<<<(2 * 256 * 128 + 255) / 256, 256, 0, stream>>>(Wsb, Bt);

    int gb = (tot + 255) / 256;
    hist2_k<<<dim3(gb, 2), 256, 0, stream>>>(ei0, ei1, cnt0, cnt1, e, n);
    scan_red_k<<<dim3(nb, 2), 256, 0, stream>>>(cnt0, cnt1, part, n, nb);
    scan_mid_k<<<2, 1024, 0, stream>>>(part, nb);
    scan_off_k<<<dim3(nb, 2), 256, 0, stream>>>(cnt0, cnt1, part, off0, off1, n, nb);

    a_canon_k<<<(n + 3) / 4, 256, 0, stream>>>(x_raw, xb, vecs, avals, n, flag);
    gemm_h<<<dim3((n + 127) / 128, 2), 256, 0, stream>>>(xb, Bt, h0, n);

    fill2_k<<<dim3(gb, 2), 256, 0, stream>>>(ei0, ei1, avals, off0, off1,
                                             pair0, pair1, e, n);

    agg_k<<<(n + 3) / 4, 256, 0, stream>>>(off0, pair0, off1, pair1,
                                           h0, h1, bsb, d_out, n, flag);
}

// Round 6
// 500.640 us; speedup vs baseline: 2.8922x; 1.0816x over previous
//
#include <hip/hip_runtime.h>

typedef __attribute__((ext_vector_type(8))) __bf16 bf16x8;
typedef __attribute__((ext_vector_type(4))) float floatx4;

__device__ __forceinline__ float bf2f(unsigned short u) {
    return __uint_as_float(((unsigned)u) << 16);
}
__device__ __forceinline__ unsigned short f2bf(float f) {
    unsigned u = __float_as_uint(f);
    unsigned r = u + 0x7FFFu + ((u >> 16) & 1u);
    return (unsigned short)(r >> 16);
}

// ---------------------------------------------------------------------------
// Dtype sniffing: bf16 tensors -> even ushorts have sane exponents ~100%;
// fp32 tensors (viewed as ushorts) -> ~25%.
__global__ void detect_k(const unsigned short* __restrict__ xs, int* __restrict__ flag) {
    __shared__ int sred[256];
    int tid = threadIdx.x;
    int cnt = 0;
    for (int j = 0; j < 16; ++j) {
        unsigned short u = xs[(tid * 16 + j) * 2];
        int e = (u >> 7) & 0xFF;
        cnt += (e >= 96 && e <= 159) ? 1 : 0;
    }
    sred[tid] = cnt;
    __syncthreads();
    for (int s = 128; s > 0; s >>= 1) {
        if (tid < s) sred[tid] += sred[tid + s];
        __syncthreads();
    }
    if (tid == 0) *flag = (sred[0] > 2048) ? 1 : 0;  // 1 = bf16, 0 = fp32
}

__device__ __forceinline__ void canon8(const void* src, unsigned short* dst,
                                       long long idx, int f) {
    if (f) {
        *(uint4*)&dst[idx] = *(const uint4*)((const unsigned short*)src + idx);
    } else {
        const float* sf = (const float*)src;
        unsigned short v[8];
        for (int j = 0; j < 8; ++j) v[j] = f2bf(sf[idx + j]);
        *(uint4*)&dst[idx] = *(const uint4*)v;
    }
}

// one launch canonicalizes Ws, Wd, att_src, att_dst, bias
__global__ void canon5_k(const void* Ws, const void* Wd, const void* as,
                         const void* ad, const void* b,
                         unsigned short* Wsb, unsigned short* Wdb,
                         unsigned short* asb, unsigned short* adb,
                         unsigned short* bsb, const int* __restrict__ flag) {
    int blk = blockIdx.x, tid = threadIdx.x;
    int f = *flag;
    if (blk < 64) {
        const void* src = blk < 32 ? Ws : Wd;
        unsigned short* dst = blk < 32 ? Wsb : Wdb;
        long long idx = ((long long)(blk & 31) * 256 + tid) * 8;
        canon8(src, dst, idx, f);
    } else {
        if (tid < 32)       canon8(as, asb, (long long)tid * 8, f);
        else if (tid < 64)  canon8(ad, adb, (long long)(tid - 32) * 8, f);
        else if (tid < 96)  canon8(b,  bsb, (long long)(tid - 64) * 8, f);
    }
}

// ---------------------------------------------------------------------------
// wsvec[r][k] = sum_h W_src[r][k][h]*att_src[r][h];  wdvec likewise.
__global__ void vec_kernel(const unsigned short* __restrict__ Ws,
                           const unsigned short* __restrict__ Wd,
                           const unsigned short* __restrict__ as_,
                           const unsigned short* __restrict__ ad_,
                           float* __restrict__ vecs) {
    int r = blockIdx.x;        // 0..1
    int k = threadIdx.x;       // 0..255
    float s = 0.f, t = 0.f;
    const unsigned short* wsrow = Ws + (size_t)r * 32768 + (size_t)k * 128;
    const unsigned short* wdrow = Wd + (size_t)r * 32768 + (size_t)k * 128;
    for (int h = 0; h < 128; ++h) {
        s += bf2f(wsrow[h]) * bf2f(as_[r * 128 + h]);
        t += bf2f(wdrow[h]) * bf2f(ad_[r * 128 + h]);
    }
    vecs[(r * 2 + 0) * 256 + k] = s;
    vecs[(r * 2 + 1) * 256 + k] = t;
}

// Bt[r][n][k] = W_src[r][k][n]  (bf16, transposed for k-contiguous MFMA frags)
__global__ void transpose_W(const unsigned short* __restrict__ W,
                            unsigned short* __restrict__ Bt) {
    int i = blockIdx.x * 256 + threadIdx.x;
    if (i >= 2 * 256 * 128) return;
    int r = i >> 15, rem = i & 32767;
    int k = rem >> 7, n = rem & 127;
    Bt[(size_t)r * 32768 + n * 256 + k] = W[i];
}

// ---------------------------------------------------------------------------
// Fused: canonicalize x into xb AND compute the 4 per-node attention scalars.
__global__ __launch_bounds__(256) void a_canon_k(const void* __restrict__ xraw,
                                                 unsigned short* __restrict__ xb,
                                                 const float* __restrict__ vecs,
                                                 float* __restrict__ aout, int n,
                                                 const int* __restrict__ flag) {
    __shared__ float sv[1024];
    int tid = threadIdx.x;
    for (int j = 0; j < 4; ++j) sv[j * 256 + tid] = vecs[j * 256 + tid];
    __syncthreads();
    int lane = tid & 63, wave = tid >> 6;
    int row = blockIdx.x * 4 + wave;
    if (row >= n) return;
    float xf[4];
    if (*flag) {
        uint2 u = *(const uint2*)((const unsigned short*)xraw + (size_t)row * 256 + lane * 4);
        xf[0] = bf2f((unsigned short)(u.x & 0xFFFF));
        xf[1] = bf2f((unsigned short)(u.x >> 16));
        xf[2] = bf2f((unsigned short)(u.y & 0xFFFF));
        xf[3] = bf2f((unsigned short)(u.y >> 16));
        *(uint2*)&xb[(size_t)row * 256 + lane * 4] = u;
    } else {
        float4 f = *(const float4*)((const float*)xraw + (size_t)row * 256 + lane * 4);
        xf[0] = f.x; xf[1] = f.y; xf[2] = f.z; xf[3] = f.w;
        unsigned short v[4] = {f2bf(f.x), f2bf(f.y), f2bf(f.z), f2bf(f.w)};
        *(uint2*)&xb[(size_t)row * 256 + lane * 4] = *(const uint2*)v;
    }
    float s[4] = {0.f, 0.f, 0.f, 0.f};
    for (int j = 0; j < 4; ++j)
        for (int q = 0; q < 4; ++q)
            s[j] += xf[q] * sv[j * 256 + lane * 4 + q];
    for (int j = 0; j < 4; ++j)
        for (int off = 32; off > 0; off >>= 1)
            s[j] += __shfl_down(s[j], off);
    if (lane == 0)
        for (int j = 0; j < 4; ++j) aout[(size_t)j * n + row] = s[j];
}

// ---------------------------------------------------------------------------
// h[r] = x @ W_src[r]  (bf16 in, bf16 out).  Tile: 128 rows x 128 cols, BK=32.
__global__ __launch_bounds__(256) void gemm_h(const unsigned short* __restrict__ x,
                                              const unsigned short* __restrict__ Btg,
                                              unsigned short* __restrict__ hout, int n) {
    const int r = blockIdx.y;
    const unsigned short* bt = Btg + (size_t)r * 32768;
    unsigned short* h = hout + (size_t)r * n * 128;
    const int r0 = blockIdx.x * 128;
    __shared__ __align__(16) unsigned short As[128 * 40];
    __shared__ __align__(16) unsigned short Bs[128 * 40];
    int tid = threadIdx.x;
    int lane = tid & 63, wave = tid >> 6;

    floatx4 acc[2][8];
    for (int mt = 0; mt < 2; ++mt)
        for (int nt = 0; nt < 8; ++nt)
            acc[mt][nt] = (floatx4){0.f, 0.f, 0.f, 0.f};

    for (int k0 = 0; k0 < 256; k0 += 32) {
        for (int i = 0; i < 2; ++i) {
            int L = i * 256 + tid;
            int row = L >> 2, kc = (L & 3) * 8;
            uint4 va = make_uint4(0u, 0u, 0u, 0u);
            int gr = r0 + row;
            if (gr < n) va = *(const uint4*)&x[(size_t)gr * 256 + k0 + kc];
            *(uint4*)&As[row * 40 + kc] = va;
            uint4 vb = *(const uint4*)&bt[(size_t)row * 256 + k0 + kc];
            *(uint4*)&Bs[row * 40 + kc] = vb;
        }
        __syncthreads();
        int qk = (lane >> 4) * 8;
        int m16 = lane & 15;
        bf16x8 af[2], bfv[8];
        af[0] = *(const bf16x8*)&As[(wave * 32 + m16) * 40 + qk];
        af[1] = *(const bf16x8*)&As[(wave * 32 + 16 + m16) * 40 + qk];
        for (int nt = 0; nt < 8; ++nt)
            bfv[nt] = *(const bf16x8*)&Bs[(nt * 16 + m16) * 40 + qk];
        for (int mt = 0; mt < 2; ++mt)
            for (int nt = 0; nt < 8; ++nt)
                acc[mt][nt] = __builtin_amdgcn_mfma_f32_16x16x32_bf16(
                    af[mt], bfv[nt], acc[mt][nt], 0, 0, 0);
        __syncthreads();
    }
    int col0 = lane & 15;
    for (int mt = 0; mt < 2; ++mt) {
        int baser = r0 + wave * 32 + mt * 16 + (lane >> 4) * 4;
        for (int nt = 0; nt < 8; ++nt)
            for (int i = 0; i < 4; ++i) {
                int gr = baser + i;
                if (gr < n) h[(size_t)gr * 128 + nt * 16 + col0] = f2bf(acc[mt][nt][i]);
            }
    }
}

// ---------------------------------------------------------------------------
// CSR build. hist also records each edge's within-segment rank, so the fill
// pass needs NO atomics and `off` stays pristine (exclusive starts).
__global__ void hist2_k(const int* __restrict__ ei0, const int* __restrict__ ei1,
                        int* __restrict__ cnt0, int* __restrict__ cnt1,
                        int* __restrict__ rank0, int* __restrict__ rank1,
                        int E_, int n) {
    int rel = blockIdx.y;
    const int* ei = rel ? ei1 : ei0;
    int* cnt = rel ? cnt1 : cnt0;
    int* rank = rel ? rank1 : rank0;
    int t = blockIdx.x * 256 + threadIdx.x;
    if (t >= E_ + n) return;
    int d = (t < E_) ? ei[E_ + t] : (t - E_);
    rank[t] = atomicAdd(&cnt[d], 1);
}

// phase 1: per-block (256-elem tile) reduction -> partial[rel][b]
__global__ __launch_bounds__(256) void scan_red_k(const int* __restrict__ cnt0,
                                                  const int* __restrict__ cnt1,
                                                  int* __restrict__ part, // [2][nb]
                                                  int n, int nb) {
    __shared__ int s[256];
    int rel = blockIdx.y;
    const int* cnt = rel ? cnt1 : cnt0;
    int i = blockIdx.x * 256 + threadIdx.x;
    s[threadIdx.x] = (i < n) ? cnt[i] : 0;
    __syncthreads();
    for (int o = 128; o > 0; o >>= 1) {
        if (threadIdx.x < o) s[threadIdx.x] += s[threadIdx.x + o];
        __syncthreads();
    }
    if (threadIdx.x == 0) part[rel * nb + blockIdx.x] = s[0];
}

// phase 2: one block, exclusive-scan the partials per relation (nb <= 1024)
__global__ __launch_bounds__(1024) void scan_mid_k(int* __restrict__ part, int nb) {
    __shared__ int s[1024];
    int rel = blockIdx.x;
    int t = threadIdx.x;
    s[t] = (t < nb) ? part[rel * nb + t] : 0;
    __syncthreads();
    for (int o = 1; o < 1024; o <<= 1) {
        int v = (t >= o) ? s[t - o] : 0;
        __syncthreads();
        s[t] += v;
        __syncthreads();
    }
    if (t < nb) part[rel * nb + t] = (t == 0) ? 0 : s[t - 1];
}

// phase 3: block-local inclusive scan + base -> exclusive off[i]
__global__ __launch_bounds__(256) void scan_off_k(const int* __restrict__ cnt0,
                                                  const int* __restrict__ cnt1,
                                                  const int* __restrict__ part,
                                                  int* __restrict__ off0,
                                                  int* __restrict__ off1,
                                                  int n, int nb) {
    __shared__ int s[256];
    int rel = blockIdx.y;
    const int* cnt = rel ? cnt1 : cnt0;
    int* off = rel ? off1 : off0;
    int i = blockIdx.x * 256 + threadIdx.x;
    int t = threadIdx.x;
    int v = (i < n) ? cnt[i] : 0;
    s[t] = v;
    __syncthreads();
    for (int o = 1; o < 256; o <<= 1) {
        int u = (t >= o) ? s[t - o] : 0;
        __syncthreads();
        s[t] += u;
        __syncthreads();
    }
    if (i < n) off[i] = part[rel * nb + blockIdx.x] + s[t] - v;
}

// fill (atomic-free): pos = off[d] + rank[t]; pair[pos] = (e, src)
__global__ void fill2_k(const int* __restrict__ ei0, const int* __restrict__ ei1,
                        const float* __restrict__ avals,
                        const int* __restrict__ off0, const int* __restrict__ off1,
                        const int* __restrict__ rank0, const int* __restrict__ rank1,
                        unsigned long long* __restrict__ pair0,
                        unsigned long long* __restrict__ pair1,
                        int E_, int n) {
    int rel = blockIdx.y;
    const int* ei = rel ? ei1 : ei0;
    const float* as_ = avals + (rel ? 2 * (size_t)n : 0);
    const float* ad_ = avals + (rel ? 3 * (size_t)n : (size_t)n);
    const int* off = rel ? off1 : off0;
    const int* rank = rel ? rank1 : rank0;
    unsigned long long* pair = rel ? pair1 : pair0;
    int t = blockIdx.x * 256 + threadIdx.x;
    if (t >= E_ + n) return;
    int s, d;
    if (t < E_) { s = ei[t]; d = ei[E_ + t]; } else { s = t - E_; d = s; }
    float e = as_[s] + ad_[d];
    e = e > 0.f ? e : 0.2f * e;
    int pos = off[d] + rank[t];
    pair[pos] = ((unsigned long long)__float_as_uint(e) << 32) | (unsigned)s;
}

// ---------------------------------------------------------------------------
// One wave per dst node; 4 groups x 16 lanes, 2x unrolled -> 8 edges in
// flight. Branchless tail: clamp index, mask weight to 0.
__device__ __forceinline__ void acc8(float* a, float w, const uint4& hv) {
    a[0] += w * bf2f((unsigned short)(hv.x & 0xFFFFu));
    a[1] += w * bf2f((unsigned short)(hv.x >> 16));
    a[2] += w * bf2f((unsigned short)(hv.y & 0xFFFFu));
    a[3] += w * bf2f((unsigned short)(hv.y >> 16));
    a[4] += w * bf2f((unsigned short)(hv.z & 0xFFFFu));
    a[5] += w * bf2f((unsigned short)(hv.z >> 16));
    a[6] += w * bf2f((unsigned short)(hv.w & 0xFFFFu));
    a[7] += w * bf2f((unsigned short)(hv.w >> 16));
}

__device__ __forceinline__ void rel_acc4(int d, int g, int l, int lane,
                                         const int* __restrict__ off,
                                         const int* __restrict__ cnt,
                                         const unsigned long long* __restrict__ pair,
                                         const unsigned short* __restrict__ h,
                                         float* __restrict__ o /*[8]*/) {
    int s0 = off[d];
    int e0 = s0 + cnt[d];
    float m = -1e30f;
    for (int i = s0 + lane; i < e0; i += 64)
        m = fmaxf(m, __uint_as_float((unsigned)(pair[i] >> 32)));
    for (int o_ = 1; o_ < 64; o_ <<= 1) m = fmaxf(m, __shfl_xor(m, o_));
    float denom = 0.f;
    float a[8] = {0.f, 0.f, 0.f, 0.f, 0.f, 0.f, 0.f, 0.f};
    int last = e0 - 1;  // deg >= 1 always (self-loop)
    for (int base = s0; base < e0; base += 8) {
        int i0 = base + g, i1 = i0 + 4;
        int j0 = min(i0, last), j1 = min(i1, last);
        unsigned long long p0 = pair[j0];
        unsigned long long p1 = pair[j1];
        int sA = (int)(unsigned)p0;
        int sB = (int)(unsigned)p1;
        uint4 hv0 = *(const uint4*)&h[(size_t)sA * 128 + l * 8];
        uint4 hv1 = *(const uint4*)&h[(size_t)sB * 128 + l * 8];
        float w0 = __expf(__uint_as_float((unsigned)(p0 >> 32)) - m);
        float w1 = __expf(__uint_as_float((unsigned)(p1 >> 32)) - m);
        w0 = (i0 < e0) ? w0 : 0.f;
        w1 = (i1 < e0) ? w1 : 0.f;
        denom += w0 + w1;
        acc8(a, w0, hv0);
        acc8(a, w1, hv1);
    }
    for (int j = 0; j < 8; ++j) {
        a[j] += __shfl_xor(a[j], 16);
        a[j] += __shfl_xor(a[j], 32);
    }
    denom += __shfl_xor(denom, 16);
    denom += __shfl_xor(denom, 32);
    float inv = 1.f / (denom + 1e-16f);
    for (int j = 0; j < 8; ++j) o[j] = a[j] * inv;
}

__global__ __launch_bounds__(256) void agg_k(
    const int* __restrict__ off0, const int* __restrict__ cnt0,
    const unsigned long long* __restrict__ pair0,
    const int* __restrict__ off1, const int* __restrict__ cnt1,
    const unsigned long long* __restrict__ pair1,
    const unsigned short* __restrict__ h0, const unsigned short* __restrict__ h1,
    const unsigned short* __restrict__ bias, void* __restrict__ out,
    int n, const int* __restrict__ flag) {
    int wave = threadIdx.x >> 6, lane = threadIdx.x & 63;
    int g = lane >> 4, l = lane & 15;
    int d = blockIdx.x * 4 + wave;
    if (d >= n) return;
    float p[8], q[8];
    rel_acc4(d, g, l, lane, off0, cnt0, pair0, h0, p);
    rel_acc4(d, g, l, lane, off1, cnt1, pair1, h1, q);
    uint4 b0 = *(const uint4*)&bias[l * 8];
    uint4 b1 = *(const uint4*)&bias[128 + l * 8];
    const unsigned* b0u = (const unsigned*)&b0;
    const unsigned* b1u = (const unsigned*)&b1;
    float v[8];
    for (int j = 0; j < 8; ++j) {
        unsigned w0 = b0u[j >> 1], w1 = b1u[j >> 1];
        float bb = bf2f((unsigned short)((j & 1) ? (w0 >> 16) : (w0 & 0xFFFFu)))
                 + bf2f((unsigned short)((j & 1) ? (w1 >> 16) : (w1 & 0xFFFFu)));
        float t = p[j] + q[j] + bb;
        v[j] = t > 0.f ? t : (__expf(t) - 1.f);
    }
    if (g == 0) {
        if (*flag) {
            unsigned pk[4];
            for (int j = 0; j < 4; ++j)
                pk[j] = ((unsigned)f2bf(v[2 * j + 1]) << 16) | (unsigned)f2bf(v[2 * j]);
            ((uint4*)out)[(size_t)d * 16 + l] = *(const uint4*)pk;
        } else {
            float4 f0 = make_float4(v[0], v[1], v[2], v[3]);
            float4 f1 = make_float4(v[4], v[5], v[6], v[7]);
            ((float4*)out)[(size_t)d * 32 + l * 2] = f0;
            ((float4*)out)[(size_t)d * 32 + l * 2 + 1] = f1;
        }
    }
}

// ---------------------------------------------------------------------------
static inline char* carve(char*& p, size_t bytes) {
    char* r = p;
    p += (bytes + 255) & ~(size_t)255;
    return r;
}

extern "C" void kernel_launch(void* const* d_in, const int* in_sizes, int n_in,
                              void* d_out, int out_size, void* d_ws, size_t ws_size,
                              hipStream_t stream) {
    (void)n_in; (void)out_size; (void)ws_size;
    const void* x_raw  = d_in[0];
    const int*  ei0    = (const int*)d_in[1];
    const int*  ei1    = (const int*)d_in[2];
    const void* Ws_raw = d_in[3];
    const void* Wd_raw = d_in[4];
    const void* as_raw = d_in[5];
    const void* ad_raw = d_in[6];
    const void* b_raw  = d_in[7];

    const int n = in_sizes[0] / 256;   // 100000
    const int e = in_sizes[1] / 2;     // 1000000
    const int tot = e + n;
    const int nb = (n + 255) / 256;    // scan blocks per relation (<=1024)

    // workspace carve-up
    char* p = (char*)d_ws;
    float* avals = (float*)carve(p, (size_t)4 * n * 4);   // as0, ad0, as1, ad1
    int*   cnt0  = (int*)carve(p, (size_t)2 * n * 4);     // cnt0 + cnt1 (one memset)
    int*   cnt1  = cnt0 + n;
    int*   off0  = (int*)carve(p, (size_t)n * 4);
    int*   off1  = (int*)carve(p, (size_t)n * 4);
    int*   part  = (int*)carve(p, (size_t)2 * nb * 4);
    int*   rank0 = (int*)carve(p, (size_t)tot * 4);
    int*   rank1 = (int*)carve(p, (size_t)tot * 4);
    unsigned long long* pair0 = (unsigned long long*)carve(p, (size_t)tot * 8);
    unsigned long long* pair1 = (unsigned long long*)carve(p, (size_t)tot * 8);
    float* vecs  = (float*)carve(p, 1024 * 4);
    int*   flag  = (int*)carve(p, 256);
    unsigned short* xb  = (unsigned short*)carve(p, (size_t)n * 256 * 2);
    unsigned short* h0  = (unsigned short*)carve(p, (size_t)2 * n * 128 * 2);
    unsigned short* h1  = h0 + (size_t)n * 128;
    unsigned short* Wsb = (unsigned short*)carve(p, 65536 * 2);
    unsigned short* Wdb = (unsigned short*)carve(p, 65536 * 2);
    unsigned short* Bt  = (unsigned short*)carve(p, 65536 * 2);
    unsigned short* asb = (unsigned short*)carve(p, 256 * 2);
    unsigned short* adb = (unsigned short*)carve(p, 256 * 2);
    unsigned short* bsb = (unsigned short*)carve(p, 256 * 2);

    hipMemsetAsync(cnt0, 0, (size_t)2 * n * 4, stream);

    detect_k<<<1, 256, 0, stream>>>((const unsigned short*)x_raw, flag);
    canon5_k<<<65, 256, 0, stream>>>(Ws_raw, Wd_raw, as_raw, ad_raw, b_raw,
                                     Wsb, Wdb, asb, adb, bsb, flag);
    vec_kernel<<<2, 256, 0, stream>>>(Wsb, Wdb, asb, adb, vecs);
    transpose_W<<<(2 * 256 * 128 + 255) / 256, 256, 0, stream>>>(Wsb, Bt);

    int gb = (tot + 255) / 256;
    hist2_k<<<dim3(gb, 2), 256, 0, stream>>>(ei0, ei1, cnt0, cnt1, rank0, rank1, e, n);
    scan_red_k<<<dim3(nb, 2), 256, 0, stream>>>(cnt0, cnt1, part, n, nb);
    scan_mid_k<<<2, 1024, 0, stream>>>(part, nb);
    scan_off_k<<<dim3(nb, 2), 256, 0, stream>>>(cnt0, cnt1, part, off0, off1, n, nb);

    a_canon_k<<<(n + 3) / 4, 256, 0, stream>>>(x_raw, xb, vecs, avals, n, flag);
    gemm_h<<<dim3((n + 127) / 128, 2), 256, 0, stream>>>(xb, Bt, h0, n);

    fill2_k<<<dim3(gb, 2), 256, 0, stream>>>(ei0, ei1, avals, off0, off1,
                                             rank0, rank1, pair0, pair1, e, n);

    agg_k<<<(n + 3) / 4, 256, 0, stream>>>(off0, cnt0, pair0, off1, cnt1, pair1,
                                           h0, h1, bsb, d_out, n, flag);
}